// Round 6
// baseline (3968.662 us; speedup 1.0000x reference)
//
#include <hip/hip_runtime.h>

#define NSTEP 27

typedef _Float16 f16;
typedef __attribute__((ext_vector_type(8))) _Float16 f16x8;
typedef __attribute__((ext_vector_type(4))) float f32x4;

#define MFMA(a, b, c) __builtin_amdgcn_mfma_f32_16x16x32_f16(a, b, c, 0, 0, 0)

__device__ __forceinline__ float sigmoidf_(float x) { return 1.0f / (1.0f + expf(-x)); }
__device__ __forceinline__ float softplusf_(float x) { return x > 20.0f ? x : log1pf(expf(x)); }

// ---------------- f16 workspace arena ----------------
constexpr long OFF_WI   = 0;                         // [3072][3072]
constexpr long OFF_WH   = OFF_WI   + 3072L * 3072;   // [3072][1024]
constexpr long OFF_WPX1 = OFF_WH   + 3072L * 1024;   // [16][32]
constexpr long OFF_WPX2 = OFF_WPX1 + 512;            // [16][160]
constexpr long OFF_WE1  = OFF_WPX2 + 2560;           // [32][288]
constexpr long OFF_WE2  = OFF_WE1  + 9216;           // [64][288]
constexpr long OFF_WMV  = OFF_WE2  + 18432;          // [128][576]
constexpr long OFF_WPZ  = OFF_WMV  + 73728;          // [16][576]
constexpr long OFF_WPRI = OFF_WPZ  + 9216;           // [32][160]
constexpr long OFF_WPMV = OFF_WPRI + 5120;           // [128][288]
constexpr long OFF_WD1  = OFF_WPMV + 36864;          // [9216] 4 classes
constexpr long OFF_GI   = OFF_WD1  + 9216;           // [128][3072]
constexpr long OFF_F16_END = OFF_GI + 128L * 3072;

struct Params {
  const float* frame; long fstride;
  const float* eps_t;
  const f16 *wpx1, *wpx2, *we1, *we2, *wmv, *wpz, *wd1, *wpri, *wpmv;
  const f16 *wiG, *whG;
  const float *bpx1, *bpx2, *be1, *be2, *bm, *bv, *bpz, *bd1;
  const float *d2w, *d2b, *bpri, *bpm, *bpv, *gbi, *gbh;
  float *gih0, *gih1, *ghh;
  float* hG; f16* gi;
  int* ctr;            // [0..26]: h ready; [32..58]: gi ready; [64..90]: tile queue
  float *out_t, *zm, *zlv, *pm, *plv;
  int t, last;
};

// scatter fmap value at (pos=py*8+px, ic) into 8x8 s1p1-conv im2col A (padded row stride ldk)
__device__ __forceinline__ void scat8_lds(f16* __restrict__ A, int ldk, int pos, int ic, float val) {
  int py = pos >> 3, px = pos & 7;
  f16 v = (f16)val;
#pragma unroll
  for (int ky = 0; ky < 3; ++ky) {
    int oy = py + 1 - ky;
    if ((unsigned)oy >= 8u) continue;
#pragma unroll
    for (int kx = 0; kx < 3; ++kx) {
      int ox = px + 1 - kx;
      if ((unsigned)ox >= 8u) continue;
      A[(oy * 8 + ox) * ldk + ic * 9 + ky * 3 + kx] = v;
    }
  }
}

// scatter fmap value into dec1 ConvT (8->15, s2 p1) parity-class im2col (padded strides)
__device__ __forceinline__ void scatd1_lds(f16* __restrict__ Ad1, int pos, int ic, float val) {
  const int aof[4] = {0, 2560, 7168, 11776};
  const int Kp[4] = {40, 72, 72, 136};
  int py = pos >> 3, px = pos & 7;
  f16 v = (f16)val;
#pragma unroll
  for (int ky = 0; ky < 3; ++ky) {
    int y = 2 * py + ky - 1;
    if ((unsigned)y >= 15u) continue;
    int cy = y & 1;
    int nky = cy ? 2 : 1;
    int tiy = cy ? (ky >> 1) : 0;
#pragma unroll
    for (int kx = 0; kx < 3; ++kx) {
      int x = 2 * px + kx - 1;
      if ((unsigned)x >= 15u) continue;
      int cx = x & 1;
      int nkx = cx ? 2 : 1;
      int tix = cx ? (kx >> 1) : 0;
      int c = cy * 2 + cx;
      Ad1[aof[c] + ((y >> 1) * 8 + (x >> 1)) * Kp[c] + ic * (nky * nkx) + tiy * nkx + tix] = v;
    }
  }
}

// one 64x32 GRU GEMM tile. idx: 0..191 wh (z=2), 192..383 wi lo (z=0), 384..575 wi hi (z=1).
__device__ __forceinline__ void gru_tile(const Params& P, int idx, int lane) {
  int lm = lane & 15, q8 = lane >> 4;
  int z, gw;
  if (idx < 192) { z = 2; gw = idx; }
  else { int j = idx - 192; z = j / 192; gw = j - z * 192; }
  int mg = gw & 1, ng = gw >> 1;
  const f16* A = (z == 2) ? P.gi + 2048 : P.gi;
  const f16* B = (z == 2) ? P.whG : P.wiG;
  int K = (z == 2) ? 1024 : 1536;
  int k0 = (z == 1) ? 1536 : 0;
  long ldb = (z == 2) ? 1024 : 3072;
  float* outp = (z == 0) ? P.gih0 : (z == 1) ? P.gih1 : P.ghh;
  int m0 = mg * 64, n0 = ng * 32;
  f32x4 acc[4][2] = {};
  const f16* Ap = A + (long)(m0 + lm) * 3072 + k0 + q8 * 8;
  const f16* Bp = B + (long)(n0 + lm) * ldb + k0 + q8 * 8;
#pragma unroll 2
  for (int k = 0; k < K; k += 32) {
    f16x8 b0 = *(const f16x8*)(Bp + k);
    f16x8 b1 = *(const f16x8*)(Bp + 16 * ldb + k);
#pragma unroll
    for (int i = 0; i < 4; ++i) {
      f16x8 a = *(const f16x8*)(Ap + (long)i * 16 * 3072 + k);
      acc[i][0] = MFMA(a, b0, acc[i][0]);
      acc[i][1] = MFMA(a, b1, acc[i][1]);
    }
  }
#pragma unroll
  for (int i = 0; i < 4; ++i)
#pragma unroll
    for (int j = 0; j < 2; ++j)
#pragma unroll
      for (int r = 0; r < 4; ++r)
        outp[(long)(m0 + i * 16 + q8 * 4 + r) * 3072 + n0 + j * 16 + lm] = acc[i][j][r];
}

// ---------------- setup: weight fp32 -> f16 packing ----------------
__global__ __launch_bounds__(256) void k_wpack(const float* __restrict__ src, f16* __restrict__ dst,
                                               int N, int Ks, int Kd) {
  int tot = N * Kd, stride = gridDim.x * 256;
  for (int i = blockIdx.x * 256 + threadIdx.x; i < tot; i += stride) {
    int n = i / Kd, k = i - n * Kd;
    dst[i] = (k < Ks) ? (f16)src[n * Ks + k] : (f16)0.f;
  }
}

__global__ __launch_bounds__(256) void k_wd1(const float* __restrict__ src, f16* __restrict__ dst) {
  int i = blockIdx.x * 256 + threadIdx.x;
  if (i >= 9216) return;
  int c, base;
  if (i < 1024) { c = 0; base = 0; }
  else if (i < 3072) { c = 1; base = 1024; }
  else if (i < 5120) { c = 2; base = 3072; }
  else { c = 3; base = 5120; }
  const int Kc[4] = {32, 64, 64, 128};
  int j = i - base, K = Kc[c];
  int oc = j / K, k = j - oc * K;
  int cy = c >> 1, cx = c & 1;
  int nky = cy ? 2 : 1, nkx = cx ? 2 : 1, ntap = nky * nkx;
  int ic = k / ntap, tap = k - ic * ntap;
  int tiy = tap / nkx, tix = tap - tiy * nkx;
  int ky = (nky == 1) ? 1 : tiy * 2;
  int kx = (nkx == 1) ? 1 : tix * 2;
  dst[i] = (f16)src[((ic * 32 + oc) * 3 + ky) * 3 + kx];
}

// =================== fused step + GRU kernel ===================
// grid 192 (all co-resident, 1 block/CU): blocks 0-127 = per-batch step (round-4 code +
// ready signals); blocks 128-191 = GRU workers. Each worker WAVE claims one 64x32 tile
// from an atomic queue (wh tiles first); 960 worker waves >= 576 tiles so all tiles are
// claimed instantly and execute in parallel the moment their gate opens. Gates mirrored
// to an LDS flag by one poller wave per block (no L2 spin storm). Step blocks steal
// leftover tiles after their dec tail (safety net). One-way dependency -> deadlock-free.
__global__ __launch_bounds__(1024) void k_step(Params P) {
  __shared__ f16 lds[78336];
  int tid = threadIdx.x;
  int wv = tid >> 6, lane = tid & 63, lm = lane & 15, q = lane >> 4;

  if (blockIdx.x >= 128) {
    // ================= GRU worker blocks =================
    if (P.t >= NSTEP - 1) return;          // last step needs no next-h
    volatile int* flag = (volatile int*)lds;   // [0]=h-ready, [1]=gi-ready
    if (tid < 2) flag[tid] = 0;
    __syncthreads();
    if (wv == 0) {
      // poller wave: mirror global ready counters into block-local LDS flags
      if (lane == 0) {
        while (atomicAdd(P.ctr + P.t, 0) < 128) __builtin_amdgcn_s_sleep(8);
        flag[0] = 1;
        while (atomicAdd(P.ctr + 32 + P.t, 0) < 128) __builtin_amdgcn_s_sleep(8);
        flag[1] = 1;
      }
      return;
    }
    int* qc = P.ctr + 64 + P.t;
    for (;;) {
      int idx = 0;
      if (lane == 0) idx = atomicAdd(qc, 1);
      idx = __shfl(idx, 0);
      if (idx >= 576) return;
      int g = (idx < 192) ? 0 : 1;
      while (!flag[g]) __builtin_amdgcn_s_sleep(8);   // block-local LDS spin
      __threadfence();                                 // acquire before reading gi
      gru_tile(P, idx, lane);
    }
  }

  // ================= step half (blocks 0-127) =================
  f16* hbuf = lds;
  f16* B1 = lds + 1024;
  f16* B2 = lds + 38400;
  f16* B3 = lds + 57344;
  f16* A1 = B3;
  f16* frame = B3 + 10240;
  f16* A2 = B3 + 10240;

  int b = blockIdx.x;
  f32x4 z4 = {};

  // ---- GRU gates of previous step -> h_t (1 element/thread) ----
  {
    int i = tid;
    float hn = 0.f;
    if (P.t) {
      long o = (long)b * 3072 + i;
      float ir  = P.gih0[o] + P.gih1[o] + P.gbi[i];
      float iz  = P.gih0[o + 1024] + P.gih1[o + 1024] + P.gbi[i + 1024];
      float in_ = P.gih0[o + 2048] + P.gih1[o + 2048] + P.gbi[i + 2048];
      float hr  = P.ghh[o] + P.gbh[i];
      float hz  = P.ghh[o + 1024] + P.gbh[i + 1024];
      float hnn = P.ghh[o + 2048] + P.gbh[i + 2048];
      float r = sigmoidf_(ir + hr), u = sigmoidf_(iz + hz);
      float ng = tanhf(in_ + r * hnn);
      hn = (1.f - u) * ng + u * P.hG[b * 1024 + i];
    }
    P.hG[b * 1024 + i] = hn;
    hbuf[i] = (f16)hn;
    P.gi[(long)b * 3072 + 2048 + i] = (f16)hn;
  }
  // ---- stage input frame ----
  const float* fr = P.frame + (long)b * P.fstride;
  for (int i = tid; i < 3072; i += 1024) frame[i] = (f16)fr[i];
  __syncthreads();
  // signal: h-part of gi committed -> unlock wh GRU tiles
  if (tid == 0) { __threadfence(); atomicAdd(P.ctr + P.t, 1); }
  // ---- A1 build (tid<512, 2 threads/row)  ||  zero B1,B2 (tid>=512) ----
  if (tid < 512) {
    int row = tid >> 1, half = tid & 1;
    int oy = row >> 4, ox = row & 15;
    f16* rp = A1 + row * 40;
    if (half == 0) {
#pragma unroll
      for (int ic = 0; ic < 2; ++ic)
#pragma unroll
        for (int ky = 0; ky < 3; ++ky) {
          int y = 2 * oy + ky - 1;
#pragma unroll
          for (int kx = 0; kx < 3; ++kx) {
            int x = 2 * ox + kx - 1;
            rp[ic * 9 + ky * 3 + kx] =
                ((unsigned)y < 32u && (unsigned)x < 32u) ? frame[ic * 1024 + y * 32 + x] : (f16)0;
          }
        }
    } else {
#pragma unroll
      for (int ky = 0; ky < 3; ++ky) {
        int y = 2 * oy + ky - 1;
#pragma unroll
        for (int kx = 0; kx < 3; ++kx) {
          int x = 2 * ox + kx - 1;
          rp[18 + ky * 3 + kx] =
              ((unsigned)y < 32u && (unsigned)x < 32u) ? frame[2048 + y * 32 + x] : (f16)0;
        }
      }
#pragma unroll
      for (int k = 27; k < 40; ++k) rp[k] = (f16)0;
    }
  } else {
    int4 zz = {0, 0, 0, 0};
    int t2 = tid - 512;
    for (int i = t2; i < 18944 / 8; i += 512) ((int4*)B2)[i] = zz;
    for (int i = t2; i < 37376 / 8; i += 512) ((int4*)B1)[i] = zz;
  }
  __syncthreads();
  // ---- zero A2 (overlays dead frame) ----
  {
    int4 zz = {0, 0, 0, 0};
    for (int i = tid; i < 10752 / 8; i += 1024) ((int4*)A2)[i] = zz;
  }
  __syncthreads();
  // ---- h -> enc1 im2col (ic 16..31), 1 element/thread ----
  scat8_lds(B2, 296, tid & 63, 16 + (tid >> 6), (float)hbuf[tid]);
  // ---- psix1: M=256 (1 m-tile/wave over 16 waves), N=16, K=32; relu -> s2 scatter to A2 ----
  {
    f16x8 bf = *(const f16x8*)(P.wpx1 + lm * 32 + q * 8);
    float bb = P.bpx1[lm];
    int mt = wv;
    f16x8 a = *(const f16x8*)(A1 + (mt * 16 + lm) * 40 + q * 8);
    f32x4 acc = MFMA(a, bf, z4);
#pragma unroll
    for (int r = 0; r < 4; ++r) {
      int m = mt * 16 + q * 4 + r;
      float val = fmaxf(acc[r] + bb, 0.f);
      int y = m >> 4, x = m & 15;
      f16 v = (f16)val;
#pragma unroll
      for (int ky = 0; ky < 3; ++ky) {
        int ty = y + 1 - ky;
        if (ty < 0 || (ty & 1)) continue;
        int oy = ty >> 1; if (oy >= 8) continue;
#pragma unroll
        for (int kx = 0; kx < 3; ++kx) {
          int tx = x + 1 - kx;
          if (tx < 0 || (tx & 1)) continue;
          int ox = tx >> 1; if (ox >= 8) continue;
          A2[(oy * 8 + ox) * 168 + lm * 9 + ky * 3 + kx] = v;
        }
      }
    }
  }
  __syncthreads();
  // ---- psix2: M=64 (waves 0..3), N=16, K=160; relu -> gi + enc1 im2col (ic 0..15) ----
  if (wv < 4) {
    f32x4 acc = {};
#pragma unroll
    for (int k = 0; k < 160; k += 32) {
      f16x8 a = *(const f16x8*)(A2 + (wv * 16 + lm) * 168 + k + q * 8);
      f16x8 bf = *(const f16x8*)(P.wpx2 + lm * 160 + k + q * 8);
      acc = MFMA(a, bf, acc);
    }
    float bb = P.bpx2[lm];
#pragma unroll
    for (int r = 0; r < 4; ++r) {
      int pos = wv * 16 + q * 4 + r;
      float val = fmaxf(acc[r] + bb, 0.f);
      P.gi[(long)b * 3072 + lm * 64 + pos] = (f16)val;
      scat8_lds(B2, 296, pos, lm, val);
    }
  }
  __syncthreads();
  // ---- enc1: waves 0-7 GEMM (M=64,N=32); waves 8-15 h -> dec1 class-im2col (ic 0..15) ----
  {
    int nt = wv & 1, mt = (wv >> 1) & 3;
    f32x4 a0 = {};
    if (wv < 8) {
#pragma unroll
      for (int k = 0; k < 288; k += 32) {
        f16x8 bf = *(const f16x8*)(P.we1 + (nt * 16 + lm) * 288 + k + q * 8);
        f16x8 x0 = *(const f16x8*)(B2 + (mt * 16 + lm) * 296 + k + q * 8);
        a0 = MFMA(x0, bf, a0);
      }
    } else {
      int i0 = (wv - 8) * 128 + lane;
      scatd1_lds(B3, i0 & 63, i0 >> 6, (float)hbuf[i0]);
      int i1 = i0 + 64;
      scatd1_lds(B3, i1 & 63, i1 >> 6, (float)hbuf[i1]);
    }
    __syncthreads();
    if (wv < 8) {
      float bb = P.be1[nt * 16 + lm];
#pragma unroll
      for (int r = 0; r < 4; ++r)
        scat8_lds(B2, 296, mt * 16 + q * 4 + r, nt * 16 + lm, fmaxf(a0[r] + bb, 0.f));
    }
  }
  __syncthreads();
  // ---- enc2: M=64 (4 m-tiles), N=64 (4 n-tiles): 1 tile/wave; -> Amv (B1) ----
  {
    int nt = wv & 3, mh = wv >> 2;   // mh 0..3
    f32x4 acc = {};
#pragma unroll
    for (int k = 0; k < 288; k += 32) {
      f16x8 bf = *(const f16x8*)(P.we2 + (nt * 16 + lm) * 288 + k + q * 8);
      f16x8 a = *(const f16x8*)(B2 + ((mh)*16 + lm) * 296 + k + q * 8);
      acc = MFMA(a, bf, acc);
    }
    int ch = nt * 16 + lm;
    float bb = P.be2[ch];
#pragma unroll
    for (int r = 0; r < 4; ++r)
      scat8_lds(B1, 584, mh * 16 + q * 4 + r, ch, fmaxf(acc[r] + bb, 0.f));
  }
  __syncthreads();
  // ---- encm+encv dual: 16 waves = 4 m-tiles x 4 n-quarters, K=576; z -> Apz (B1 in place) ----
  {
    f32x4 am = {}, av = {};
    int nq = wv & 3, mh = wv >> 2;   // mh 0..3
    int ch = nq * 16 + lm;
    // prefetch eps (independent of K loop; pulls HBM latency off the critical path)
    const float4 ev = *(const float4*)(P.eps_t + (long)b * 4096 + ch * 64 + mh * 16 + q * 4);
    float evr[4] = {ev.x, ev.y, ev.z, ev.w};
#pragma unroll
    for (int k = 0; k < 576; k += 32) {
      f16x8 bm = *(const f16x8*)(P.wmv + (long)ch * 576 + k + q * 8);
      f16x8 bv = *(const f16x8*)(P.wmv + (long)(64 + ch) * 576 + k + q * 8);
      f16x8 a = *(const f16x8*)(B1 + (mh * 16 + lm) * 584 + k + q * 8);
      am = MFMA(a, bm, am);
      av = MFMA(a, bv, av);
    }
    __syncthreads();
    float bbm = P.bm[ch], bbv = P.bv[ch];
#pragma unroll
    for (int r = 0; r < 4; ++r) {
      int pos = mh * 16 + q * 4 + r;
      float zmv = am[r] + bbm;
      float sp = softplusf_(av[r] + bbv);
      float zval = zmv + sp * evr[r];
      if (P.last) {
        P.zm[(long)b * 4096 + ch * 64 + pos] = zmv;
        P.zlv[(long)b * 4096 + ch * 64 + pos] = sp;
      }
      scat8_lds(B1, 584, pos, ch, zval);
    }
  }
  __syncthreads();
  // ---- psiz: M=64 (waves 0..3), N=16, K=576; relu -> gi + dec1 class-im2col (ic 16..31) ----
  if (wv < 4) {
    f32x4 acc = {};
#pragma unroll
    for (int k = 0; k < 576; k += 32) {
      f16x8 a = *(const f16x8*)(B1 + (wv * 16 + lm) * 584 + k + q * 8);
      f16x8 bf = *(const f16x8*)(P.wpz + (long)lm * 576 + k + q * 8);
      acc = MFMA(a, bf, acc);
    }
    float bb = P.bpz[lm];
#pragma unroll
    for (int r = 0; r < 4; ++r) {
      int pos = wv * 16 + q * 4 + r;
      float val = fmaxf(acc[r] + bb, 0.f);
      P.gi[(long)b * 3072 + 1024 + lm * 64 + pos] = (f16)val;
      scatd1_lds(B3, pos, 16 + lm, val);
    }
  }
  __syncthreads();
  // signal: gi fully committed -> unlock wi GRU tiles (overlap with dec tail below)
  if (tid == 0) { __threadfence(); atomicAdd(P.ctr + 32 + P.t, 1); }
  // ---- dec1 ConvT via 4 parity-class GEMMs: 2 classes/wave (16 waves) -> d1f (B2, 240) ----
  {
    int nt = wv & 1, mt = (wv >> 1) & 3, cb = wv >> 3;  // cb 0..1 -> classes {cb, cb+2}
#pragma unroll
    for (int cc = 0; cc < 2; ++cc) {
      int c = cb + cc * 2;
      int cy = c >> 1, cx = c & 1;
      int Kc = 32 << (cy + cx);
      int Kp = Kc + 8;
      int aof = cy ? (cx ? 11776 : 7168) : (cx ? 2560 : 0);
      int bof = cy ? (cx ? 5120 : 3072) : (cx ? 1024 : 0);
      f32x4 acc = {};
      for (int k = 0; k < Kc; k += 32) {
        f16x8 a = *(const f16x8*)(B3 + aof + (mt * 16 + lm) * Kp + k + q * 8);
        f16x8 bf = *(const f16x8*)(P.wd1 + bof + (nt * 16 + lm) * Kc + k + q * 8);
        acc = MFMA(a, bf, acc);
      }
      int oc = nt * 16 + lm;
      float bb = P.bd1[oc];
#pragma unroll
      for (int r = 0; r < 4; ++r) {
        int m = mt * 16 + q * 4 + r;
        int y = 2 * (m >> 3) + cy, x = 2 * (m & 7) + cx;
        if (y < 15 && x < 15)
          B2[oc * 240 + y * 15 + x] = (f16)fmaxf(acc[r] + bb, 0.f);
      }
    }
  }
  __syncthreads();
  // ---- dec2 ConvT 15->32 (direct, parity x y-quad per wave), sigmoid -> out ----
  {
    int p = wv & 3, jh = wv >> 2;     // jh 0..3
    int cy2 = p >> 1, cx2 = p & 1;
    int lx = lane & 15, ly = lane >> 4;
    int x = 2 * lx + cx2;
    float acc0 = P.d2b[0], acc1 = P.d2b[1], acc2 = P.d2b[2];
    int nky = cy2 ? 1 : 2, nkx = cx2 ? 1 : 2;
    int py = jh * 4 + ly;
    for (int ic = 0; ic < 32; ++ic) {
      const f16* sp = B2 + ic * 240;
      const float* wic = P.d2w + ic * 27;
      for (int ty = 0; ty < nky; ++ty) {
        int ky = cy2 ? 1 : ty * 2;
        int iy = (2 * py + cy2 - ky) >> 1;
        bool yv = (unsigned)iy < 15u;
        for (int tx = 0; tx < nkx; ++tx) {
          int kx = cx2 ? 1 : tx * 2;
          int ix = (x - kx) >> 1;
          if (yv && (unsigned)ix < 15u) {
            float v = (float)sp[iy * 15 + ix];
            acc0 += v * wic[ky * 3 + kx];
            acc1 += v * wic[9 + ky * 3 + kx];
            acc2 += v * wic[18 + ky * 3 + kx];
          }
        }
      }
    }
    int y = 2 * py + cy2;
    P.out_t[(long)b * 82944 + 0 * 1024 + y * 32 + x] = sigmoidf_(acc0);
    P.out_t[(long)b * 82944 + 1 * 1024 + y * 32 + x] = sigmoidf_(acc1);
    P.out_t[(long)b * 82944 + 2 * 1024 + y * 32 + x] = sigmoidf_(acc2);
  }
  if (!P.last) {
    // ---- steal leftover GRU tiles (safety net; queue normally drained by workers) ----
    int* qc = P.ctr + 64 + P.t;
    for (;;) {
      int idx = 0;
      if (lane == 0) idx = atomicAdd(qc, 1);
      idx = __shfl(idx, 0);
      if (idx >= 576) break;
      int* cp = P.ctr + ((idx < 192) ? P.t : 32 + P.t);
      if (lane == 0) { while (atomicAdd(cp, 0) < 128) __builtin_amdgcn_s_sleep(8); }
      __threadfence();
      gru_tile(P, idx, lane);
    }
  } else {
    // ---- last step only: pri -> prim/priv ----
    if (tid < 64) {                 // Apri im2col of h in B3 [64][168]
      int py = tid >> 3, px = tid & 7;
      f16* rp = B3 + tid * 168;
      int k = 0;
      for (int ic = 0; ic < 16; ++ic)
        for (int ky = 0; ky < 3; ++ky) {
          int y = py + ky - 1;
          for (int kx = 0; kx < 3; ++kx, ++k) {
            int x = px + kx - 1;
            rp[k] = ((unsigned)y < 8u && (unsigned)x < 8u) ? hbuf[ic * 64 + y * 8 + x] : (f16)0;
          }
        }
      for (; k < 168; ++k) rp[k] = (f16)0;
    }
    {
      int4 zz = {0, 0, 0, 0};
      for (int i = tid; i < 18944 / 8; i += 1024) ((int4*)B1)[i] = zz;   // Apmv [64][296]
    }
    __syncthreads();
    // pri: M=64, N=32, 1 tile/wave (waves 0-7), K=160 -> scatter Apmv (B1)
    if (wv < 8) {
      int nt = wv & 1, mt = wv >> 1;
      f32x4 a0 = {};
#pragma unroll
      for (int k = 0; k < 160; k += 32) {
        f16x8 bf = *(const f16x8*)(P.wpri + (nt * 16 + lm) * 160 + k + q * 8);
        f16x8 x0 = *(const f16x8*)(B3 + (mt * 16 + lm) * 168 + k + q * 8);
        a0 = MFMA(x0, bf, a0);
      }
      float bb = P.bpri[nt * 16 + lm];
#pragma unroll
      for (int r = 0; r < 4; ++r)
        scat8_lds(B1, 296, mt * 16 + q * 4 + r, nt * 16 + lm, fmaxf(a0[r] + bb, 0.f));
    }
    __syncthreads();
    // prim+priv dual: 16 waves = 4 m-tiles x 4 n-quarters, K=288 -> pm, plv
    {
      f32x4 am = {}, av = {};
      int nq = wv & 3, mh = wv >> 2;   // mh 0..3
      int ch = nq * 16 + lm;
#pragma unroll
      for (int k = 0; k < 288; k += 32) {
        f16x8 bm = *(const f16x8*)(P.wpmv + (long)ch * 288 + k + q * 8);
        f16x8 bv = *(const f16x8*)(P.wpmv + (long)(64 + ch) * 288 + k + q * 8);
        f16x8 a = *(const f16x8*)(B1 + (mh * 16 + lm) * 296 + k + q * 8);
        am = MFMA(a, bm, am);
        av = MFMA(a, bv, av);
      }
      float bbm = P.bpm[ch], bbv = P.bpv[ch];
#pragma unroll
      for (int r = 0; r < 4; ++r) {
        int pos = mh * 16 + q * 4 + r;
        P.pm[(long)b * 4096 + ch * 64 + pos] = am[r] + bbm;
        P.plv[(long)b * 4096 + ch * 64 + pos] = softplusf_(av[r] + bbv);
      }
    }
  }
}

extern "C" void kernel_launch(void* const* d_in, const int* in_sizes, int n_in,
                              void* d_out, int out_size, void* d_ws, size_t ws_size,
                              hipStream_t stream) {
  const float* x       = (const float*)d_in[0];
  const float* eps     = (const float*)d_in[1];
  const float* psix1_w = (const float*)d_in[2];
  const float* psix1_b = (const float*)d_in[3];
  const float* psix2_w = (const float*)d_in[4];
  const float* psix2_b = (const float*)d_in[5];
  const float* psiz_w  = (const float*)d_in[6];
  const float* psiz_b  = (const float*)d_in[7];
  const float* enc1_w  = (const float*)d_in[8];
  const float* enc1_b  = (const float*)d_in[9];
  const float* enc2_w  = (const float*)d_in[10];
  const float* enc2_b  = (const float*)d_in[11];
  const float* encm_w  = (const float*)d_in[12];
  const float* encm_b  = (const float*)d_in[13];
  const float* encv_w  = (const float*)d_in[14];
  const float* encv_b  = (const float*)d_in[15];
  const float* pri_w   = (const float*)d_in[16];
  const float* pri_b   = (const float*)d_in[17];
  const float* prim_w  = (const float*)d_in[18];
  const float* prim_b  = (const float*)d_in[19];
  const float* priv_w  = (const float*)d_in[20];
  const float* priv_b  = (const float*)d_in[21];
  const float* dec1_w  = (const float*)d_in[22];
  const float* dec1_b  = (const float*)d_in[23];
  const float* dec2_w  = (const float*)d_in[24];
  const float* dec2_b  = (const float*)d_in[25];
  const float* gru_wi  = (const float*)d_in[26];
  const float* gru_wh  = (const float*)d_in[27];
  const float* gru_bi  = (const float*)d_in[28];
  const float* gru_bh  = (const float*)d_in[29];

  float* out = (float*)d_out;
  float* zm_out  = out + 10616832;
  float* zlv_out = zm_out + 524288;
  float* pm_out  = zlv_out + 524288;
  float* plv_out = pm_out + 524288;

  f16* ws16 = (f16*)d_ws;
  f16* wi_f  = ws16 + OFF_WI;
  f16* wh_f  = ws16 + OFF_WH;
  f16* w_px1 = ws16 + OFF_WPX1;
  f16* w_px2 = ws16 + OFF_WPX2;
  f16* w_e1  = ws16 + OFF_WE1;
  f16* w_e2  = ws16 + OFF_WE2;
  f16* w_mv  = ws16 + OFF_WMV;
  f16* w_pz  = ws16 + OFF_WPZ;
  f16* w_pri = ws16 + OFF_WPRI;
  f16* w_pmv = ws16 + OFF_WPMV;
  f16* w_d1  = ws16 + OFF_WD1;
  f16* gi    = ws16 + OFF_GI;
  float* fws = (float*)(ws16 + OFF_F16_END);
  float* gih0 = fws;                 // 393216
  float* gih1 = gih0 + 393216;       // 393216
  float* ghh  = gih1 + 393216;       // 393216
  float* hG   = ghh + 393216;        // 131072
  int*   ctr  = (int*)(hG + 131072); // 128 ints: h-ready / gi-ready / tile queues

  hipMemsetAsync(ctr, 0, 128 * sizeof(int), stream);

  k_wpack<<<2048, 256, 0, stream>>>(gru_wi, wi_f, 3072, 3072, 3072);
  k_wpack<<<1024, 256, 0, stream>>>(gru_wh, wh_f, 3072, 1024, 1024);
  k_wpack<<<2, 256, 0, stream>>>(psix1_w, w_px1, 16, 27, 32);
  k_wpack<<<10, 256, 0, stream>>>(psix2_w, w_px2, 16, 144, 160);
  k_wpack<<<36, 256, 0, stream>>>(enc1_w, w_e1, 32, 288, 288);
  k_wpack<<<72, 256, 0, stream>>>(enc2_w, w_e2, 64, 288, 288);
  k_wpack<<<144, 256, 0, stream>>>(encm_w, w_mv, 64, 576, 576);
  k_wpack<<<144, 256, 0, stream>>>(encv_w, w_mv + 64L * 576, 64, 576, 576);
  k_wpack<<<36, 256, 0, stream>>>(psiz_w, w_pz, 16, 576, 576);
  k_wpack<<<20, 256, 0, stream>>>(pri_w, w_pri, 32, 144, 160);
  k_wpack<<<72, 256, 0, stream>>>(prim_w, w_pmv, 64, 288, 288);
  k_wpack<<<72, 256, 0, stream>>>(priv_w, w_pmv + 64L * 288, 64, 288, 288);
  k_wd1<<<36, 256, 0, stream>>>(dec1_w, w_d1);

  for (int t = 0; t < NSTEP; ++t) {
    Params P;
    P.frame = (t < 6) ? x + (long)t * 3072 : out + (long)(t - 1) * 3072;
    P.fstride = (t < 6) ? 86016 : 82944;
    P.eps_t = eps + (long)t * 524288;
    P.wpx1 = w_px1; P.wpx2 = w_px2; P.we1 = w_e1; P.we2 = w_e2;
    P.wmv = w_mv; P.wpz = w_pz; P.wd1 = w_d1; P.wpri = w_pri; P.wpmv = w_pmv;
    P.wiG = wi_f; P.whG = wh_f;
    P.bpx1 = psix1_b; P.bpx2 = psix2_b; P.be1 = enc1_b; P.be2 = enc2_b;
    P.bm = encm_b; P.bv = encv_b; P.bpz = psiz_b; P.bd1 = dec1_b;
    P.d2w = dec2_w; P.d2b = dec2_b; P.bpri = pri_b; P.bpm = prim_b; P.bpv = priv_b;
    P.gbi = gru_bi; P.gbh = gru_bh;
    P.gih0 = gih0; P.gih1 = gih1; P.ghh = ghh;
    P.hG = hG; P.gi = gi;
    P.ctr = ctr;
    P.out_t = out + (long)t * 3072;
    P.zm = zm_out; P.zlv = zlv_out; P.pm = pm_out; P.plv = plv_out;
    P.t = t; P.last = (t == NSTEP - 1);
    k_step<<<192, 1024, 0, stream>>>(P);
  }
}

// Round 7
// 2873.118 us; speedup vs baseline: 1.3813x; 1.3813x over previous
//
#include <hip/hip_runtime.h>

#define NSTEP 27

typedef _Float16 f16;
typedef __attribute__((ext_vector_type(8))) _Float16 f16x8;
typedef __attribute__((ext_vector_type(4))) float f32x4;

#define MFMA(a, b, c) __builtin_amdgcn_mfma_f32_16x16x32_f16(a, b, c, 0, 0, 0)

__device__ __forceinline__ float sigmoidf_(float x) { return 1.0f / (1.0f + expf(-x)); }
__device__ __forceinline__ float softplusf_(float x) { return x > 20.0f ? x : log1pf(expf(x)); }

// ---------------- f16 workspace arena ----------------
constexpr long OFF_WI   = 0;                         // [3072][3072]
constexpr long OFF_WH   = OFF_WI   + 3072L * 3072;   // [3072][1024]
constexpr long OFF_WPX1 = OFF_WH   + 3072L * 1024;   // [16][32]
constexpr long OFF_WPX2 = OFF_WPX1 + 512;            // [16][160]
constexpr long OFF_WE1  = OFF_WPX2 + 2560;           // [32][288]
constexpr long OFF_WE2  = OFF_WE1  + 9216;           // [64][288]
constexpr long OFF_WMV  = OFF_WE2  + 18432;          // [128][576]
constexpr long OFF_WPZ  = OFF_WMV  + 73728;          // [16][576]
constexpr long OFF_WPRI = OFF_WPZ  + 9216;           // [32][160]
constexpr long OFF_WPMV = OFF_WPRI + 5120;           // [128][288]
constexpr long OFF_WD1  = OFF_WPMV + 36864;          // [9216] 4 classes
constexpr long OFF_GI   = OFF_WD1  + 9216;           // [128][3072]
constexpr long OFF_F16_END = OFF_GI + 128L * 3072;

struct Params {
  const float* frame; long fstride;
  const float* eps_t;
  const f16 *wpx1, *wpx2, *we1, *we2, *wmv, *wpz, *wd1, *wpri, *wpmv;
  const float *bpx1, *bpx2, *be1, *be2, *bm, *bv, *bpz, *bd1;
  const float *d2w, *d2b, *bpri, *bpm, *bpv, *gbi, *gbh;
  const float *gih0, *gih1, *ghh;
  float* hG; f16* gi;
  float *out_t, *zm, *zlv, *pm, *plv;
  int t, last;
};

// scatter fmap value at (pos=py*8+px, ic) into 8x8 s1p1-conv im2col A (padded row stride ldk)
__device__ __forceinline__ void scat8_lds(f16* __restrict__ A, int ldk, int pos, int ic, float val) {
  int py = pos >> 3, px = pos & 7;
  f16 v = (f16)val;
#pragma unroll
  for (int ky = 0; ky < 3; ++ky) {
    int oy = py + 1 - ky;
    if ((unsigned)oy >= 8u) continue;
#pragma unroll
    for (int kx = 0; kx < 3; ++kx) {
      int ox = px + 1 - kx;
      if ((unsigned)ox >= 8u) continue;
      A[(oy * 8 + ox) * ldk + ic * 9 + ky * 3 + kx] = v;
    }
  }
}

// scatter fmap value into dec1 ConvT (8->15, s2 p1) parity-class im2col (padded strides)
__device__ __forceinline__ void scatd1_lds(f16* __restrict__ Ad1, int pos, int ic, float val) {
  const int aof[4] = {0, 2560, 7168, 11776};
  const int Kp[4] = {40, 72, 72, 136};
  int py = pos >> 3, px = pos & 7;
  f16 v = (f16)val;
#pragma unroll
  for (int ky = 0; ky < 3; ++ky) {
    int y = 2 * py + ky - 1;
    if ((unsigned)y >= 15u) continue;
    int cy = y & 1;
    int nky = cy ? 2 : 1;
    int tiy = cy ? (ky >> 1) : 0;
#pragma unroll
    for (int kx = 0; kx < 3; ++kx) {
      int x = 2 * px + kx - 1;
      if ((unsigned)x >= 15u) continue;
      int cx = x & 1;
      int nkx = cx ? 2 : 1;
      int tix = cx ? (kx >> 1) : 0;
      int c = cy * 2 + cx;
      Ad1[aof[c] + ((y >> 1) * 8 + (x >> 1)) * Kp[c] + ic * (nky * nkx) + tiy * nkx + tix] = v;
    }
  }
}

// ---------------- setup: weight fp32 -> f16 packing ----------------
__global__ __launch_bounds__(256) void k_wpack(const float* __restrict__ src, f16* __restrict__ dst,
                                               int N, int Ks, int Kd) {
  int tot = N * Kd, stride = gridDim.x * 256;
  for (int i = blockIdx.x * 256 + threadIdx.x; i < tot; i += stride) {
    int n = i / Kd, k = i - n * Kd;
    dst[i] = (k < Ks) ? (f16)src[n * Ks + k] : (f16)0.f;
  }
}

__global__ __launch_bounds__(256) void k_wd1(const float* __restrict__ src, f16* __restrict__ dst) {
  int i = blockIdx.x * 256 + threadIdx.x;
  if (i >= 9216) return;
  int c, base;
  if (i < 1024) { c = 0; base = 0; }
  else if (i < 3072) { c = 1; base = 1024; }
  else if (i < 5120) { c = 2; base = 3072; }
  else { c = 3; base = 5120; }
  const int Kc[4] = {32, 64, 64, 128};
  int j = i - base, K = Kc[c];
  int oc = j / K, k = j - oc * K;
  int cy = c >> 1, cx = c & 1;
  int nky = cy ? 2 : 1, nkx = cx ? 2 : 1, ntap = nky * nkx;
  int ic = k / ntap, tap = k - ic * ntap;
  int tiy = tap / nkx, tix = tap - tiy * nkx;
  int ky = (nky == 1) ? 1 : tiy * 2;
  int kx = (nkx == 1) ? 1 : tix * 2;
  dst[i] = (f16)src[((ic * 32 + oc) * 3 + ky) * 3 + kx];
}

// =================== fused per-batch step kernel (round-4 verified, 76.4 us) ===================
// 1 block = 1 batch, 1024 threads (16 waves -> 4 waves/SIMD). 1 block/CU (153KB LDS).
// LDS (f16 units): hbuf [16][64] @0 | B1 [64][584] @1024 | B2 [64][296] @38400 |
//   B3 @57344: A1 [256][40], frame/A2 [64][168] @B3+10240; later Ad1 (20480) / Apri.
__global__ __launch_bounds__(1024) void k_step(Params P) {
  __shared__ f16 lds[78336];
  f16* hbuf = lds;
  f16* B1 = lds + 1024;
  f16* B2 = lds + 38400;
  f16* B3 = lds + 57344;
  f16* A1 = B3;
  f16* frame = B3 + 10240;
  f16* A2 = B3 + 10240;

  int b = blockIdx.x, tid = threadIdx.x;
  int wv = tid >> 6, lane = tid & 63, lm = lane & 15, q = lane >> 4;
  f32x4 z4 = {};

  // ---- GRU gates of previous step -> h_t (1 element/thread) ----
  {
    int i = tid;
    float hn = 0.f;
    if (P.t) {
      long o = (long)b * 3072 + i;
      float ir  = P.gih0[o] + P.gih1[o] + P.gbi[i];
      float iz  = P.gih0[o + 1024] + P.gih1[o + 1024] + P.gbi[i + 1024];
      float in_ = P.gih0[o + 2048] + P.gih1[o + 2048] + P.gbi[i + 2048];
      float hr  = P.ghh[o] + P.gbh[i];
      float hz  = P.ghh[o + 1024] + P.gbh[i + 1024];
      float hnn = P.ghh[o + 2048] + P.gbh[i + 2048];
      float r = sigmoidf_(ir + hr), u = sigmoidf_(iz + hz);
      float ng = tanhf(in_ + r * hnn);
      hn = (1.f - u) * ng + u * P.hG[b * 1024 + i];
    }
    P.hG[b * 1024 + i] = hn;
    hbuf[i] = (f16)hn;
    P.gi[(long)b * 3072 + 2048 + i] = (f16)hn;
  }
  // ---- stage input frame ----
  const float* fr = P.frame + (long)b * P.fstride;
  for (int i = tid; i < 3072; i += 1024) frame[i] = (f16)fr[i];
  __syncthreads();
  // ---- A1 build (tid<512, 2 threads/row)  ||  zero B1,B2 (tid>=512) ----
  if (tid < 512) {
    int row = tid >> 1, half = tid & 1;
    int oy = row >> 4, ox = row & 15;
    f16* rp = A1 + row * 40;
    if (half == 0) {
#pragma unroll
      for (int ic = 0; ic < 2; ++ic)
#pragma unroll
        for (int ky = 0; ky < 3; ++ky) {
          int y = 2 * oy + ky - 1;
#pragma unroll
          for (int kx = 0; kx < 3; ++kx) {
            int x = 2 * ox + kx - 1;
            rp[ic * 9 + ky * 3 + kx] =
                ((unsigned)y < 32u && (unsigned)x < 32u) ? frame[ic * 1024 + y * 32 + x] : (f16)0;
          }
        }
    } else {
#pragma unroll
      for (int ky = 0; ky < 3; ++ky) {
        int y = 2 * oy + ky - 1;
#pragma unroll
        for (int kx = 0; kx < 3; ++kx) {
          int x = 2 * ox + kx - 1;
          rp[18 + ky * 3 + kx] =
              ((unsigned)y < 32u && (unsigned)x < 32u) ? frame[2048 + y * 32 + x] : (f16)0;
        }
      }
#pragma unroll
      for (int k = 27; k < 40; ++k) rp[k] = (f16)0;
    }
  } else {
    int4 zz = {0, 0, 0, 0};
    int t2 = tid - 512;
    for (int i = t2; i < 18944 / 8; i += 512) ((int4*)B2)[i] = zz;
    for (int i = t2; i < 37376 / 8; i += 512) ((int4*)B1)[i] = zz;
  }
  __syncthreads();
  // ---- zero A2 (overlays dead frame) ----
  {
    int4 zz = {0, 0, 0, 0};
    for (int i = tid; i < 10752 / 8; i += 1024) ((int4*)A2)[i] = zz;
  }
  __syncthreads();
  // ---- h -> enc1 im2col (ic 16..31), 1 element/thread ----
  scat8_lds(B2, 296, tid & 63, 16 + (tid >> 6), (float)hbuf[tid]);
  // ---- psix1: M=256 (1 m-tile/wave over 16 waves), N=16, K=32; relu -> s2 scatter to A2 ----
  {
    f16x8 bf = *(const f16x8*)(P.wpx1 + lm * 32 + q * 8);
    float bb = P.bpx1[lm];
    int mt = wv;
    f16x8 a = *(const f16x8*)(A1 + (mt * 16 + lm) * 40 + q * 8);
    f32x4 acc = MFMA(a, bf, z4);
#pragma unroll
    for (int r = 0; r < 4; ++r) {
      int m = mt * 16 + q * 4 + r;
      float val = fmaxf(acc[r] + bb, 0.f);
      int y = m >> 4, x = m & 15;
      f16 v = (f16)val;
#pragma unroll
      for (int ky = 0; ky < 3; ++ky) {
        int ty = y + 1 - ky;
        if (ty < 0 || (ty & 1)) continue;
        int oy = ty >> 1; if (oy >= 8) continue;
#pragma unroll
        for (int kx = 0; kx < 3; ++kx) {
          int tx = x + 1 - kx;
          if (tx < 0 || (tx & 1)) continue;
          int ox = tx >> 1; if (ox >= 8) continue;
          A2[(oy * 8 + ox) * 168 + lm * 9 + ky * 3 + kx] = v;
        }
      }
    }
  }
  __syncthreads();
  // ---- psix2: M=64 (waves 0..3), N=16, K=160; relu -> gi + enc1 im2col (ic 0..15) ----
  if (wv < 4) {
    f32x4 acc = {};
#pragma unroll
    for (int k = 0; k < 160; k += 32) {
      f16x8 a = *(const f16x8*)(A2 + (wv * 16 + lm) * 168 + k + q * 8);
      f16x8 bf = *(const f16x8*)(P.wpx2 + lm * 160 + k + q * 8);
      acc = MFMA(a, bf, acc);
    }
    float bb = P.bpx2[lm];
#pragma unroll
    for (int r = 0; r < 4; ++r) {
      int pos = wv * 16 + q * 4 + r;
      float val = fmaxf(acc[r] + bb, 0.f);
      P.gi[(long)b * 3072 + lm * 64 + pos] = (f16)val;
      scat8_lds(B2, 296, pos, lm, val);
    }
  }
  __syncthreads();
  // ---- enc1: waves 0-7 GEMM (M=64,N=32); waves 8-15 h -> dec1 class-im2col (ic 0..15) ----
  {
    int nt = wv & 1, mt = (wv >> 1) & 3;
    f32x4 a0 = {};
    if (wv < 8) {
#pragma unroll
      for (int k = 0; k < 288; k += 32) {
        f16x8 bf = *(const f16x8*)(P.we1 + (nt * 16 + lm) * 288 + k + q * 8);
        f16x8 x0 = *(const f16x8*)(B2 + (mt * 16 + lm) * 296 + k + q * 8);
        a0 = MFMA(x0, bf, a0);
      }
    } else {
      int i0 = (wv - 8) * 128 + lane;
      scatd1_lds(B3, i0 & 63, i0 >> 6, (float)hbuf[i0]);
      int i1 = i0 + 64;
      scatd1_lds(B3, i1 & 63, i1 >> 6, (float)hbuf[i1]);
    }
    __syncthreads();
    if (wv < 8) {
      float bb = P.be1[nt * 16 + lm];
#pragma unroll
      for (int r = 0; r < 4; ++r)
        scat8_lds(B2, 296, mt * 16 + q * 4 + r, nt * 16 + lm, fmaxf(a0[r] + bb, 0.f));
    }
  }
  __syncthreads();
  // ---- enc2: M=64 (4 m-tiles), N=64 (4 n-tiles): 1 tile/wave; -> Amv (B1) ----
  {
    int nt = wv & 3, mh = wv >> 2;   // mh 0..3
    f32x4 acc = {};
#pragma unroll
    for (int k = 0; k < 288; k += 32) {
      f16x8 bf = *(const f16x8*)(P.we2 + (nt * 16 + lm) * 288 + k + q * 8);
      f16x8 a = *(const f16x8*)(B2 + ((mh)*16 + lm) * 296 + k + q * 8);
      acc = MFMA(a, bf, acc);
    }
    int ch = nt * 16 + lm;
    float bb = P.be2[ch];
#pragma unroll
    for (int r = 0; r < 4; ++r)
      scat8_lds(B1, 584, mh * 16 + q * 4 + r, ch, fmaxf(acc[r] + bb, 0.f));
  }
  __syncthreads();
  // ---- encm+encv dual: 16 waves = 4 m-tiles x 4 n-quarters, K=576; z -> Apz (B1 in place) ----
  {
    f32x4 am = {}, av = {};
    int nq = wv & 3, mh = wv >> 2;   // mh 0..3
    int ch = nq * 16 + lm;
    // prefetch eps (independent of K loop; pulls HBM latency off the critical path)
    const float4 ev = *(const float4*)(P.eps_t + (long)b * 4096 + ch * 64 + mh * 16 + q * 4);
    float evr[4] = {ev.x, ev.y, ev.z, ev.w};
#pragma unroll
    for (int k = 0; k < 576; k += 32) {
      f16x8 bm = *(const f16x8*)(P.wmv + (long)ch * 576 + k + q * 8);
      f16x8 bv = *(const f16x8*)(P.wmv + (long)(64 + ch) * 576 + k + q * 8);
      f16x8 a = *(const f16x8*)(B1 + (mh * 16 + lm) * 584 + k + q * 8);
      am = MFMA(a, bm, am);
      av = MFMA(a, bv, av);
    }
    __syncthreads();
    float bbm = P.bm[ch], bbv = P.bv[ch];
#pragma unroll
    for (int r = 0; r < 4; ++r) {
      int pos = mh * 16 + q * 4 + r;
      float zmv = am[r] + bbm;
      float sp = softplusf_(av[r] + bbv);
      float zval = zmv + sp * evr[r];
      if (P.last) {
        P.zm[(long)b * 4096 + ch * 64 + pos] = zmv;
        P.zlv[(long)b * 4096 + ch * 64 + pos] = sp;
      }
      scat8_lds(B1, 584, pos, ch, zval);
    }
  }
  __syncthreads();
  // ---- psiz: M=64 (waves 0..3), N=16, K=576; relu -> gi + dec1 class-im2col (ic 16..31) ----
  if (wv < 4) {
    f32x4 acc = {};
#pragma unroll
    for (int k = 0; k < 576; k += 32) {
      f16x8 a = *(const f16x8*)(B1 + (wv * 16 + lm) * 584 + k + q * 8);
      f16x8 bf = *(const f16x8*)(P.wpz + (long)lm * 576 + k + q * 8);
      acc = MFMA(a, bf, acc);
    }
    float bb = P.bpz[lm];
#pragma unroll
    for (int r = 0; r < 4; ++r) {
      int pos = wv * 16 + q * 4 + r;
      float val = fmaxf(acc[r] + bb, 0.f);
      P.gi[(long)b * 3072 + 1024 + lm * 64 + pos] = (f16)val;
      scatd1_lds(B3, pos, 16 + lm, val);
    }
  }
  __syncthreads();
  // ---- dec1 ConvT via 4 parity-class GEMMs: 2 classes/wave (16 waves) -> d1f (B2, 240) ----
  {
    int nt = wv & 1, mt = (wv >> 1) & 3, cb = wv >> 3;  // cb 0..1 -> classes {cb, cb+2}
#pragma unroll
    for (int cc = 0; cc < 2; ++cc) {
      int c = cb + cc * 2;
      int cy = c >> 1, cx = c & 1;
      int Kc = 32 << (cy + cx);
      int Kp = Kc + 8;
      int aof = cy ? (cx ? 11776 : 7168) : (cx ? 2560 : 0);
      int bof = cy ? (cx ? 5120 : 3072) : (cx ? 1024 : 0);
      f32x4 acc = {};
      for (int k = 0; k < Kc; k += 32) {
        f16x8 a = *(const f16x8*)(B3 + aof + (mt * 16 + lm) * Kp + k + q * 8);
        f16x8 bf = *(const f16x8*)(P.wd1 + bof + (nt * 16 + lm) * Kc + k + q * 8);
        acc = MFMA(a, bf, acc);
      }
      int oc = nt * 16 + lm;
      float bb = P.bd1[oc];
#pragma unroll
      for (int r = 0; r < 4; ++r) {
        int m = mt * 16 + q * 4 + r;
        int y = 2 * (m >> 3) + cy, x = 2 * (m & 7) + cx;
        if (y < 15 && x < 15)
          B2[oc * 240 + y * 15 + x] = (f16)fmaxf(acc[r] + bb, 0.f);
      }
    }
  }
  __syncthreads();
  // ---- dec2 ConvT 15->32 (direct, parity x y-quad per wave), sigmoid -> out ----
  {
    int p = wv & 3, jh = wv >> 2;     // jh 0..3
    int cy2 = p >> 1, cx2 = p & 1;
    int lx = lane & 15, ly = lane >> 4;
    int x = 2 * lx + cx2;
    float acc0 = P.d2b[0], acc1 = P.d2b[1], acc2 = P.d2b[2];
    int nky = cy2 ? 1 : 2, nkx = cx2 ? 1 : 2;
    int py = jh * 4 + ly;
    for (int ic = 0; ic < 32; ++ic) {
      const f16* sp = B2 + ic * 240;
      const float* wic = P.d2w + ic * 27;
      for (int ty = 0; ty < nky; ++ty) {
        int ky = cy2 ? 1 : ty * 2;
        int iy = (2 * py + cy2 - ky) >> 1;
        bool yv = (unsigned)iy < 15u;
        for (int tx = 0; tx < nkx; ++tx) {
          int kx = cx2 ? 1 : tx * 2;
          int ix = (x - kx) >> 1;
          if (yv && (unsigned)ix < 15u) {
            float v = (float)sp[iy * 15 + ix];
            acc0 += v * wic[ky * 3 + kx];
            acc1 += v * wic[9 + ky * 3 + kx];
            acc2 += v * wic[18 + ky * 3 + kx];
          }
        }
      }
    }
    int y = 2 * py + cy2;
    P.out_t[(long)b * 82944 + 0 * 1024 + y * 32 + x] = sigmoidf_(acc0);
    P.out_t[(long)b * 82944 + 1 * 1024 + y * 32 + x] = sigmoidf_(acc1);
    P.out_t[(long)b * 82944 + 2 * 1024 + y * 32 + x] = sigmoidf_(acc2);
  }
  // ---- last step only: pri -> prim/priv ----
  if (P.last) {
    if (tid < 64) {                 // Apri im2col of h in B3 [64][168]
      int py = tid >> 3, px = tid & 7;
      f16* rp = B3 + tid * 168;
      int k = 0;
      for (int ic = 0; ic < 16; ++ic)
        for (int ky = 0; ky < 3; ++ky) {
          int y = py + ky - 1;
          for (int kx = 0; kx < 3; ++kx, ++k) {
            int x = px + kx - 1;
            rp[k] = ((unsigned)y < 8u && (unsigned)x < 8u) ? hbuf[ic * 64 + y * 8 + x] : (f16)0;
          }
        }
      for (; k < 168; ++k) rp[k] = (f16)0;
    }
    {
      int4 zz = {0, 0, 0, 0};
      for (int i = tid; i < 18944 / 8; i += 1024) ((int4*)B1)[i] = zz;   // Apmv [64][296]
    }
    __syncthreads();
    // pri: M=64, N=32, 1 tile/wave (waves 0-7), K=160 -> scatter Apmv (B1)
    if (wv < 8) {
      int nt = wv & 1, mt = wv >> 1;
      f32x4 a0 = {};
#pragma unroll
      for (int k = 0; k < 160; k += 32) {
        f16x8 bf = *(const f16x8*)(P.wpri + (nt * 16 + lm) * 160 + k + q * 8);
        f16x8 x0 = *(const f16x8*)(B3 + (mt * 16 + lm) * 168 + k + q * 8);
        a0 = MFMA(x0, bf, a0);
      }
      float bb = P.bpri[nt * 16 + lm];
#pragma unroll
      for (int r = 0; r < 4; ++r)
        scat8_lds(B1, 296, mt * 16 + q * 4 + r, nt * 16 + lm, fmaxf(a0[r] + bb, 0.f));
    }
    __syncthreads();
    // prim+priv dual: 16 waves = 4 m-tiles x 4 n-quarters, K=288 -> pm, plv
    {
      f32x4 am = {}, av = {};
      int nq = wv & 3, mh = wv >> 2;   // mh 0..3
      int ch = nq * 16 + lm;
#pragma unroll
      for (int k = 0; k < 288; k += 32) {
        f16x8 bm = *(const f16x8*)(P.wpmv + (long)ch * 288 + k + q * 8);
        f16x8 bv = *(const f16x8*)(P.wpmv + (long)(64 + ch) * 288 + k + q * 8);
        f16x8 a = *(const f16x8*)(B1 + (mh * 16 + lm) * 296 + k + q * 8);
        am = MFMA(a, bm, am);
        av = MFMA(a, bv, av);
      }
      float bbm = P.bpm[ch], bbv = P.bpv[ch];
#pragma unroll
      for (int r = 0; r < 4; ++r) {
        int pos = mh * 16 + q * 4 + r;
        P.pm[(long)b * 4096 + ch * 64 + pos] = am[r] + bbm;
        P.plv[(long)b * 4096 + ch * 64 + pos] = softplusf_(av[r] + bbv);
      }
    }
  }
}

// =================== GRU GEMMs: 128x32 wave tiles — B (wi/wh) read ONCE per step ===================
// grid (144), 128-thread blocks (2 waves). 288 wave-tiles: tau/96 = z (0: wi k<1536 -> gih0;
// 1: wi k>=1536 -> gih1; 2: wh -> ghh), ng = tau%96, n0 = ng*32, M=128 (full batch).
// Halves L3 B-traffic vs 64x32 (each B row fed both m-halves before). A (gi) is L2-resident.
__global__ __launch_bounds__(128) void k_gru(const f16* __restrict__ gi,
                                             const f16* __restrict__ wi, const f16* __restrict__ wh,
                                             float* __restrict__ gih0, float* __restrict__ gih1,
                                             float* __restrict__ ghh) {
  int wv = threadIdx.x >> 6, lane = threadIdx.x & 63, lm = lane & 15, q = lane >> 4;
  int tau = blockIdx.x * 2 + wv;         // 0..287
  int z = tau / 96, ng = tau - z * 96;
  const f16* A = (z == 2) ? gi + 2048 : gi;
  const f16* B = (z == 2) ? wh : wi;
  int K = (z == 2) ? 1024 : 1536;
  int k0 = (z == 1) ? 1536 : 0;
  long ldb = (z == 2) ? 1024 : 3072;
  float* out = (z == 0) ? gih0 : (z == 1) ? gih1 : ghh;
  int n0 = ng * 32;
  f32x4 acc[8][2] = {};
  const f16* Ap = A + (long)lm * 3072 + k0 + q * 8;
  const f16* Bp = B + (long)(n0 + lm) * ldb + k0 + q * 8;
#pragma unroll 2
  for (int k = 0; k < K; k += 32) {
    f16x8 b0 = *(const f16x8*)(Bp + k);
    f16x8 b1 = *(const f16x8*)(Bp + 16 * ldb + k);
#pragma unroll
    for (int i = 0; i < 8; ++i) {
      f16x8 a = *(const f16x8*)(Ap + (long)i * 16 * 3072 + k);
      acc[i][0] = MFMA(a, b0, acc[i][0]);
      acc[i][1] = MFMA(a, b1, acc[i][1]);
    }
  }
#pragma unroll
  for (int i = 0; i < 8; ++i)
#pragma unroll
    for (int j = 0; j < 2; ++j)
#pragma unroll
      for (int r = 0; r < 4; ++r)
        out[(long)(i * 16 + q * 4 + r) * 3072 + n0 + j * 16 + lm] = acc[i][j][r];
}

extern "C" void kernel_launch(void* const* d_in, const int* in_sizes, int n_in,
                              void* d_out, int out_size, void* d_ws, size_t ws_size,
                              hipStream_t stream) {
  const float* x       = (const float*)d_in[0];
  const float* eps     = (const float*)d_in[1];
  const float* psix1_w = (const float*)d_in[2];
  const float* psix1_b = (const float*)d_in[3];
  const float* psix2_w = (const float*)d_in[4];
  const float* psix2_b = (const float*)d_in[5];
  const float* psiz_w  = (const float*)d_in[6];
  const float* psiz_b  = (const float*)d_in[7];
  const float* enc1_w  = (const float*)d_in[8];
  const float* enc1_b  = (const float*)d_in[9];
  const float* enc2_w  = (const float*)d_in[10];
  const float* enc2_b  = (const float*)d_in[11];
  const float* encm_w  = (const float*)d_in[12];
  const float* encm_b  = (const float*)d_in[13];
  const float* encv_w  = (const float*)d_in[14];
  const float* encv_b  = (const float*)d_in[15];
  const float* pri_w   = (const float*)d_in[16];
  const float* pri_b   = (const float*)d_in[17];
  const float* prim_w  = (const float*)d_in[18];
  const float* prim_b  = (const float*)d_in[19];
  const float* priv_w  = (const float*)d_in[20];
  const float* priv_b  = (const float*)d_in[21];
  const float* dec1_w  = (const float*)d_in[22];
  const float* dec1_b  = (const float*)d_in[23];
  const float* dec2_w  = (const float*)d_in[24];
  const float* dec2_b  = (const float*)d_in[25];
  const float* gru_wi  = (const float*)d_in[26];
  const float* gru_wh  = (const float*)d_in[27];
  const float* gru_bi  = (const float*)d_in[28];
  const float* gru_bh  = (const float*)d_in[29];

  float* out = (float*)d_out;
  float* zm_out  = out + 10616832;
  float* zlv_out = zm_out + 524288;
  float* pm_out  = zlv_out + 524288;
  float* plv_out = pm_out + 524288;

  f16* ws16 = (f16*)d_ws;
  f16* wi_f  = ws16 + OFF_WI;
  f16* wh_f  = ws16 + OFF_WH;
  f16* w_px1 = ws16 + OFF_WPX1;
  f16* w_px2 = ws16 + OFF_WPX2;
  f16* w_e1  = ws16 + OFF_WE1;
  f16* w_e2  = ws16 + OFF_WE2;
  f16* w_mv  = ws16 + OFF_WMV;
  f16* w_pz  = ws16 + OFF_WPZ;
  f16* w_pri = ws16 + OFF_WPRI;
  f16* w_pmv = ws16 + OFF_WPMV;
  f16* w_d1  = ws16 + OFF_WD1;
  f16* gi    = ws16 + OFF_GI;
  float* fws = (float*)(ws16 + OFF_F16_END);
  float* gih0 = fws;                 // 393216
  float* gih1 = gih0 + 393216;       // 393216
  float* ghh  = gih1 + 393216;       // 393216
  float* hG   = ghh + 393216;        // 131072

  k_wpack<<<2048, 256, 0, stream>>>(gru_wi, wi_f, 3072, 3072, 3072);
  k_wpack<<<1024, 256, 0, stream>>>(gru_wh, wh_f, 3072, 1024, 1024);
  k_wpack<<<2, 256, 0, stream>>>(psix1_w, w_px1, 16, 27, 32);
  k_wpack<<<10, 256, 0, stream>>>(psix2_w, w_px2, 16, 144, 160);
  k_wpack<<<36, 256, 0, stream>>>(enc1_w, w_e1, 32, 288, 288);
  k_wpack<<<72, 256, 0, stream>>>(enc2_w, w_e2, 64, 288, 288);
  k_wpack<<<144, 256, 0, stream>>>(encm_w, w_mv, 64, 576, 576);
  k_wpack<<<144, 256, 0, stream>>>(encv_w, w_mv + 64L * 576, 64, 576, 576);
  k_wpack<<<36, 256, 0, stream>>>(psiz_w, w_pz, 16, 576, 576);
  k_wpack<<<20, 256, 0, stream>>>(pri_w, w_pri, 32, 144, 160);
  k_wpack<<<72, 256, 0, stream>>>(prim_w, w_pmv, 64, 288, 288);
  k_wpack<<<72, 256, 0, stream>>>(priv_w, w_pmv + 64L * 288, 64, 288, 288);
  k_wd1<<<36, 256, 0, stream>>>(dec1_w, w_d1);

  for (int t = 0; t < NSTEP; ++t) {
    Params P;
    P.frame = (t < 6) ? x + (long)t * 3072 : out + (long)(t - 1) * 3072;
    P.fstride = (t < 6) ? 86016 : 82944;
    P.eps_t = eps + (long)t * 524288;
    P.wpx1 = w_px1; P.wpx2 = w_px2; P.we1 = w_e1; P.we2 = w_e2;
    P.wmv = w_mv; P.wpz = w_pz; P.wd1 = w_d1; P.wpri = w_pri; P.wpmv = w_pmv;
    P.bpx1 = psix1_b; P.bpx2 = psix2_b; P.be1 = enc1_b; P.be2 = enc2_b;
    P.bm = encm_b; P.bv = encv_b; P.bpz = psiz_b; P.bd1 = dec1_b;
    P.d2w = dec2_w; P.d2b = dec2_b; P.bpri = pri_b; P.bpm = prim_b; P.bpv = priv_b;
    P.gbi = gru_bi; P.gbh = gru_bh;
    P.gih0 = gih0; P.gih1 = gih1; P.ghh = ghh;
    P.hG = hG; P.gi = gi;
    P.out_t = out + (long)t * 3072;
    P.zm = zm_out; P.zlv = zlv_out; P.pm = pm_out; P.plv = plv_out;
    P.t = t; P.last = (t == NSTEP - 1);
    k_step<<<128, 1024, 0, stream>>>(P);
    if (t < NSTEP - 1)
      k_gru<<<144, 128, 0, stream>>>(gi, wi_f, wh_f, gih0, gih1, ghh);
  }
}

// Round 8
// 2718.478 us; speedup vs baseline: 1.4599x; 1.0569x over previous
//
#include <hip/hip_runtime.h>

#define NSTEP 27

typedef _Float16 f16;
typedef __attribute__((ext_vector_type(8))) _Float16 f16x8;
typedef __attribute__((ext_vector_type(4))) float f32x4;

#define MFMA(a, b, c) __builtin_amdgcn_mfma_f32_16x16x32_f16(a, b, c, 0, 0, 0)

__device__ __forceinline__ float sigmoidf_(float x) { return 1.0f / (1.0f + expf(-x)); }
__device__ __forceinline__ float softplusf_(float x) { return x > 20.0f ? x : log1pf(expf(x)); }

// ---------------- f16 workspace arena ----------------
constexpr long OFF_WI   = 0;                         // [3072][3072]
constexpr long OFF_WH   = OFF_WI   + 3072L * 3072;   // [3072][1024]
constexpr long OFF_WPX1 = OFF_WH   + 3072L * 1024;   // [16][32]
constexpr long OFF_WPX2 = OFF_WPX1 + 512;            // [16][160]
constexpr long OFF_WE1  = OFF_WPX2 + 2560;           // [32][288]
constexpr long OFF_WE2  = OFF_WE1  + 9216;           // [64][288]
constexpr long OFF_WMV  = OFF_WE2  + 18432;          // [128][576]
constexpr long OFF_WPZ  = OFF_WMV  + 73728;          // [16][576]
constexpr long OFF_WPRI = OFF_WPZ  + 9216;           // [32][160]
constexpr long OFF_WPMV = OFF_WPRI + 5120;           // [128][288]
constexpr long OFF_WD1  = OFF_WPMV + 36864;          // [9216] 4 classes
constexpr long OFF_GI   = OFF_WD1  + 9216;           // [128][3072]
constexpr long OFF_F16_END = OFF_GI + 128L * 3072;

struct Params {
  const float* frame; long fstride;
  const float* eps_t;
  const f16 *wpx1, *wpx2, *we1, *we2, *wmv, *wpz, *wd1, *wpri, *wpmv, *wiG, *whG;
  const float *bpx1, *bpx2, *be1, *be2, *bm, *bv, *bpz, *bd1;
  const float *d2w, *d2b, *bpri, *bpm, *bpv, *gbi, *gbh;
  float *gih0, *gih1, *ghh;
  float* hG; f16* gi;
  float *out_t, *zm, *zlv, *pm, *plv;
  int t, last;
};

// scatter fmap value at (pos=py*8+px, ic) into 8x8 s1p1-conv im2col A (padded row stride ldk)
__device__ __forceinline__ void scat8_lds(f16* __restrict__ A, int ldk, int pos, int ic, float val) {
  int py = pos >> 3, px = pos & 7;
  f16 v = (f16)val;
#pragma unroll
  for (int ky = 0; ky < 3; ++ky) {
    int oy = py + 1 - ky;
    if ((unsigned)oy >= 8u) continue;
#pragma unroll
    for (int kx = 0; kx < 3; ++kx) {
      int ox = px + 1 - kx;
      if ((unsigned)ox >= 8u) continue;
      A[(oy * 8 + ox) * ldk + ic * 9 + ky * 3 + kx] = v;
    }
  }
}

// scatter fmap value into dec1 ConvT (8->15, s2 p1) parity-class im2col (padded strides)
__device__ __forceinline__ void scatd1_lds(f16* __restrict__ Ad1, int pos, int ic, float val) {
  const int aof[4] = {0, 2560, 7168, 11776};
  const int Kp[4] = {40, 72, 72, 136};
  int py = pos >> 3, px = pos & 7;
  f16 v = (f16)val;
#pragma unroll
  for (int ky = 0; ky < 3; ++ky) {
    int y = 2 * py + ky - 1;
    if ((unsigned)y >= 15u) continue;
    int cy = y & 1;
    int nky = cy ? 2 : 1;
    int tiy = cy ? (ky >> 1) : 0;
#pragma unroll
    for (int kx = 0; kx < 3; ++kx) {
      int x = 2 * px + kx - 1;
      if ((unsigned)x >= 15u) continue;
      int cx = x & 1;
      int nkx = cx ? 2 : 1;
      int tix = cx ? (kx >> 1) : 0;
      int c = cy * 2 + cx;
      Ad1[aof[c] + ((y >> 1) * 8 + (x >> 1)) * Kp[c] + ic * (nky * nkx) + tiy * nkx + tix] = v;
    }
  }
}

// one 64x32 GRU GEMM tile (round-2/4 proven shape). tau: z = tau/192, gw = tau%192.
__device__ __forceinline__ void gru_tile(const Params& P, int tau, int lane) {
  int lm = lane & 15, q8 = lane >> 4;
  int z = tau / 192, gw = tau - z * 192;
  int mg = gw & 1, ng = gw >> 1;
  const f16* A = (z == 2) ? P.gi + 2048 : P.gi;
  const f16* B = (z == 2) ? P.whG : P.wiG;
  int K = (z == 2) ? 1024 : 1536;
  int k0 = (z == 1) ? 1536 : 0;
  long ldb = (z == 2) ? 1024 : 3072;
  float* outp = (z == 0) ? P.gih0 : (z == 1) ? P.gih1 : P.ghh;
  int m0 = mg * 64, n0 = ng * 32;
  f32x4 acc[4][2] = {};
  const f16* Ap = A + (long)(m0 + lm) * 3072 + k0 + q8 * 8;
  const f16* Bp = B + (long)(n0 + lm) * ldb + k0 + q8 * 8;
#pragma unroll 2
  for (int k = 0; k < K; k += 32) {
    f16x8 b0 = *(const f16x8*)(Bp + k);
    f16x8 b1 = *(const f16x8*)(Bp + 16 * ldb + k);
#pragma unroll
    for (int i = 0; i < 4; ++i) {
      f16x8 a = *(const f16x8*)(Ap + (long)i * 16 * 3072 + k);
      acc[i][0] = MFMA(a, b0, acc[i][0]);
      acc[i][1] = MFMA(a, b1, acc[i][1]);
    }
  }
#pragma unroll
  for (int i = 0; i < 4; ++i)
#pragma unroll
    for (int j = 0; j < 2; ++j)
#pragma unroll
      for (int r = 0; r < 4; ++r)
        outp[(long)(m0 + i * 16 + q8 * 4 + r) * 3072 + n0 + j * 16 + lm] = acc[i][j][r];
}

// ---------------- setup: weight fp32 -> f16 packing ----------------
__global__ __launch_bounds__(256) void k_wpack(const float* __restrict__ src, f16* __restrict__ dst,
                                               int N, int Ks, int Kd) {
  int tot = N * Kd, stride = gridDim.x * 256;
  for (int i = blockIdx.x * 256 + threadIdx.x; i < tot; i += stride) {
    int n = i / Kd, k = i - n * Kd;
    dst[i] = (k < Ks) ? (f16)src[n * Ks + k] : (f16)0.f;
  }
}

__global__ __launch_bounds__(256) void k_wd1(const float* __restrict__ src, f16* __restrict__ dst) {
  int i = blockIdx.x * 256 + threadIdx.x;
  if (i >= 9216) return;
  int c, base;
  if (i < 1024) { c = 0; base = 0; }
  else if (i < 3072) { c = 1; base = 1024; }
  else if (i < 5120) { c = 2; base = 3072; }
  else { c = 3; base = 5120; }
  const int Kc[4] = {32, 64, 64, 128};
  int j = i - base, K = Kc[c];
  int oc = j / K, k = j - oc * K;
  int cy = c >> 1, cx = c & 1;
  int nky = cy ? 2 : 1, nkx = cx ? 2 : 1, ntap = nky * nkx;
  int ic = k / ntap, tap = k - ic * ntap;
  int tiy = tap / nkx, tix = tap - tiy * nkx;
  int ky = (nky == 1) ? 1 : tiy * 2;
  int kx = (nkx == 1) ? 1 : tix * 2;
  dst[i] = (f16)src[((ic * 32 + oc) * 3 + ky) * 3 + kx];
}

// =================== head kernel: gates ... psiz (round-4 verified code minus dec tail) ===================
// 1 block = 1 batch, 1024 threads. Produces gi(t) (psix2/psiz/h) for the tail+GRU kernel.
__global__ __launch_bounds__(1024) void k_head(Params P) {
  __shared__ f16 lds[78336];
  f16* hbuf = lds;
  f16* B1 = lds + 1024;
  f16* B2 = lds + 38400;
  f16* B3 = lds + 57344;
  f16* A1 = B3;
  f16* frame = B3 + 10240;
  f16* A2 = B3 + 10240;

  int b = blockIdx.x, tid = threadIdx.x;
  int wv = tid >> 6, lane = tid & 63, lm = lane & 15, q = lane >> 4;
  f32x4 z4 = {};

  // ---- GRU gates of previous step -> h_t (1 element/thread) ----
  {
    int i = tid;
    float hn = 0.f;
    if (P.t) {
      long o = (long)b * 3072 + i;
      float ir  = P.gih0[o] + P.gih1[o] + P.gbi[i];
      float iz  = P.gih0[o + 1024] + P.gih1[o + 1024] + P.gbi[i + 1024];
      float in_ = P.gih0[o + 2048] + P.gih1[o + 2048] + P.gbi[i + 2048];
      float hr  = P.ghh[o] + P.gbh[i];
      float hz  = P.ghh[o + 1024] + P.gbh[i + 1024];
      float hnn = P.ghh[o + 2048] + P.gbh[i + 2048];
      float r = sigmoidf_(ir + hr), u = sigmoidf_(iz + hz);
      float ng = tanhf(in_ + r * hnn);
      hn = (1.f - u) * ng + u * P.hG[b * 1024 + i];
    }
    P.hG[b * 1024 + i] = hn;
    hbuf[i] = (f16)hn;
    P.gi[(long)b * 3072 + 2048 + i] = (f16)hn;
  }
  // ---- stage input frame ----
  const float* fr = P.frame + (long)b * P.fstride;
  for (int i = tid; i < 3072; i += 1024) frame[i] = (f16)fr[i];
  __syncthreads();
  // ---- A1 build (tid<512, 2 threads/row)  ||  zero B1,B2 (tid>=512) ----
  if (tid < 512) {
    int row = tid >> 1, half = tid & 1;
    int oy = row >> 4, ox = row & 15;
    f16* rp = A1 + row * 40;
    if (half == 0) {
#pragma unroll
      for (int ic = 0; ic < 2; ++ic)
#pragma unroll
        for (int ky = 0; ky < 3; ++ky) {
          int y = 2 * oy + ky - 1;
#pragma unroll
          for (int kx = 0; kx < 3; ++kx) {
            int x = 2 * ox + kx - 1;
            rp[ic * 9 + ky * 3 + kx] =
                ((unsigned)y < 32u && (unsigned)x < 32u) ? frame[ic * 1024 + y * 32 + x] : (f16)0;
          }
        }
    } else {
#pragma unroll
      for (int ky = 0; ky < 3; ++ky) {
        int y = 2 * oy + ky - 1;
#pragma unroll
        for (int kx = 0; kx < 3; ++kx) {
          int x = 2 * ox + kx - 1;
          rp[18 + ky * 3 + kx] =
              ((unsigned)y < 32u && (unsigned)x < 32u) ? frame[2048 + y * 32 + x] : (f16)0;
        }
      }
#pragma unroll
      for (int k = 27; k < 40; ++k) rp[k] = (f16)0;
    }
  } else {
    int4 zz = {0, 0, 0, 0};
    int t2 = tid - 512;
    for (int i = t2; i < 18944 / 8; i += 512) ((int4*)B2)[i] = zz;
    for (int i = t2; i < 37376 / 8; i += 512) ((int4*)B1)[i] = zz;
  }
  __syncthreads();
  // ---- zero A2 (overlays dead frame) ----
  {
    int4 zz = {0, 0, 0, 0};
    for (int i = tid; i < 10752 / 8; i += 1024) ((int4*)A2)[i] = zz;
  }
  __syncthreads();
  // ---- h -> enc1 im2col (ic 16..31), 1 element/thread ----
  scat8_lds(B2, 296, tid & 63, 16 + (tid >> 6), (float)hbuf[tid]);
  // ---- psix1: M=256 (1 m-tile/wave over 16 waves), N=16, K=32; relu -> s2 scatter to A2 ----
  {
    f16x8 bf = *(const f16x8*)(P.wpx1 + lm * 32 + q * 8);
    float bb = P.bpx1[lm];
    int mt = wv;
    f16x8 a = *(const f16x8*)(A1 + (mt * 16 + lm) * 40 + q * 8);
    f32x4 acc = MFMA(a, bf, z4);
#pragma unroll
    for (int r = 0; r < 4; ++r) {
      int m = mt * 16 + q * 4 + r;
      float val = fmaxf(acc[r] + bb, 0.f);
      int y = m >> 4, x = m & 15;
      f16 v = (f16)val;
#pragma unroll
      for (int ky = 0; ky < 3; ++ky) {
        int ty = y + 1 - ky;
        if (ty < 0 || (ty & 1)) continue;
        int oy = ty >> 1; if (oy >= 8) continue;
#pragma unroll
        for (int kx = 0; kx < 3; ++kx) {
          int tx = x + 1 - kx;
          if (tx < 0 || (tx & 1)) continue;
          int ox = tx >> 1; if (ox >= 8) continue;
          A2[(oy * 8 + ox) * 168 + lm * 9 + ky * 3 + kx] = v;
        }
      }
    }
  }
  __syncthreads();
  // ---- psix2: M=64 (waves 0..3), N=16, K=160; relu -> gi + enc1 im2col (ic 0..15) ----
  if (wv < 4) {
    f32x4 acc = {};
#pragma unroll
    for (int k = 0; k < 160; k += 32) {
      f16x8 a = *(const f16x8*)(A2 + (wv * 16 + lm) * 168 + k + q * 8);
      f16x8 bf = *(const f16x8*)(P.wpx2 + lm * 160 + k + q * 8);
      acc = MFMA(a, bf, acc);
    }
    float bb = P.bpx2[lm];
#pragma unroll
    for (int r = 0; r < 4; ++r) {
      int pos = wv * 16 + q * 4 + r;
      float val = fmaxf(acc[r] + bb, 0.f);
      P.gi[(long)b * 3072 + lm * 64 + pos] = (f16)val;
      scat8_lds(B2, 296, pos, lm, val);
    }
  }
  __syncthreads();
  // ---- enc1: waves 0-7 GEMM (M=64,N=32) ----
  {
    int nt = wv & 1, mt = (wv >> 1) & 3;
    f32x4 a0 = {};
    if (wv < 8) {
#pragma unroll
      for (int k = 0; k < 288; k += 32) {
        f16x8 bf = *(const f16x8*)(P.we1 + (nt * 16 + lm) * 288 + k + q * 8);
        f16x8 x0 = *(const f16x8*)(B2 + (mt * 16 + lm) * 296 + k + q * 8);
        a0 = MFMA(x0, bf, a0);
      }
    }
    __syncthreads();
    if (wv < 8) {
      float bb = P.be1[nt * 16 + lm];
#pragma unroll
      for (int r = 0; r < 4; ++r)
        scat8_lds(B2, 296, mt * 16 + q * 4 + r, nt * 16 + lm, fmaxf(a0[r] + bb, 0.f));
    }
  }
  __syncthreads();
  // ---- enc2: M=64 (4 m-tiles), N=64 (4 n-tiles): 1 tile/wave; -> Amv (B1) ----
  {
    int nt = wv & 3, mh = wv >> 2;   // mh 0..3
    f32x4 acc = {};
#pragma unroll
    for (int k = 0; k < 288; k += 32) {
      f16x8 bf = *(const f16x8*)(P.we2 + (nt * 16 + lm) * 288 + k + q * 8);
      f16x8 a = *(const f16x8*)(B2 + ((mh)*16 + lm) * 296 + k + q * 8);
      acc = MFMA(a, bf, acc);
    }
    int ch = nt * 16 + lm;
    float bb = P.be2[ch];
#pragma unroll
    for (int r = 0; r < 4; ++r)
      scat8_lds(B1, 584, mh * 16 + q * 4 + r, ch, fmaxf(acc[r] + bb, 0.f));
  }
  __syncthreads();
  // ---- encm+encv dual: 16 waves = 4 m-tiles x 4 n-quarters, K=576; z -> Apz (B1 in place) ----
  {
    f32x4 am = {}, av = {};
    int nq = wv & 3, mh = wv >> 2;   // mh 0..3
    int ch = nq * 16 + lm;
    const float4 ev = *(const float4*)(P.eps_t + (long)b * 4096 + ch * 64 + mh * 16 + q * 4);
    float evr[4] = {ev.x, ev.y, ev.z, ev.w};
#pragma unroll
    for (int k = 0; k < 576; k += 32) {
      f16x8 bm = *(const f16x8*)(P.wmv + (long)ch * 576 + k + q * 8);
      f16x8 bv = *(const f16x8*)(P.wmv + (long)(64 + ch) * 576 + k + q * 8);
      f16x8 a = *(const f16x8*)(B1 + (mh * 16 + lm) * 584 + k + q * 8);
      am = MFMA(a, bm, am);
      av = MFMA(a, bv, av);
    }
    __syncthreads();
    float bbm = P.bm[ch], bbv = P.bv[ch];
#pragma unroll
    for (int r = 0; r < 4; ++r) {
      int pos = mh * 16 + q * 4 + r;
      float zmv = am[r] + bbm;
      float sp = softplusf_(av[r] + bbv);
      float zval = zmv + sp * evr[r];
      if (P.last) {
        P.zm[(long)b * 4096 + ch * 64 + pos] = zmv;
        P.zlv[(long)b * 4096 + ch * 64 + pos] = sp;
      }
      scat8_lds(B1, 584, pos, ch, zval);
    }
  }
  __syncthreads();
  // ---- psiz: M=64 (waves 0..3), N=16, K=576; relu -> gi (tail kernel rebuilds Ad1) ----
  if (wv < 4) {
    f32x4 acc = {};
#pragma unroll
    for (int k = 0; k < 576; k += 32) {
      f16x8 a = *(const f16x8*)(B1 + (wv * 16 + lm) * 584 + k + q * 8);
      f16x8 bf = *(const f16x8*)(P.wpz + (long)lm * 576 + k + q * 8);
      acc = MFMA(a, bf, acc);
    }
    float bb = P.bpz[lm];
#pragma unroll
    for (int r = 0; r < 4; ++r) {
      int pos = wv * 16 + q * 4 + r;
      float val = fmaxf(acc[r] + bb, 0.f);
      P.gi[(long)b * 3072 + 1024 + lm * 64 + pos] = (f16)val;
    }
  }
}

// =================== tail + GRU kernel (launch-order synced; no gating) ===================
// grid 256, 1024 thr. Blocks 0-127: dec1+dec2 for batch b (rebuild Ad1 from gi). Blocks
// 128-255: 576 GRU 64x32 tiles, 4-5 per block on separate waves (round-4 proven tile math),
// starting immediately (gi complete at launch). At t==26: GRU blocks run pri chain instead.
__global__ __launch_bounds__(1024) void k_tailgru(Params P) {
  __shared__ f16 slds[29696];
  int tid = threadIdx.x;
  int wv = tid >> 6, lane = tid & 63, lm = lane & 15, q = lane >> 4;

  if (blockIdx.x >= 128) {
    if (!P.last) {
      // ---- GRU tiles ----
      int gb = blockIdx.x - 128;             // 0..127
      int cnt = (gb < 64) ? 5 : 4;           // 64*5 + 64*4 = 576
      int base = (gb < 64) ? gb * 5 : 320 + (gb - 64) * 4;
      if (wv < cnt) gru_tile(P, base + wv, lane);
      return;
    }
    // ---- t==26: pri -> prim/priv for batch b ----
    int b = blockIdx.x - 128;
    f16* Apri = slds;              // [64][168] = 10752
    f16* Apmv = slds + 10752;      // [64][296] = 18944
    const f16* hsrc = P.gi + (long)b * 3072 + 2048;
    if (tid < 64) {
      int py = tid >> 3, px = tid & 7;
      f16* rp = Apri + tid * 168;
      int k = 0;
      for (int ic = 0; ic < 16; ++ic)
        for (int ky = 0; ky < 3; ++ky) {
          int y = py + ky - 1;
          for (int kx = 0; kx < 3; ++kx, ++k) {
            int x = px + kx - 1;
            rp[k] = ((unsigned)y < 8u && (unsigned)x < 8u) ? hsrc[ic * 64 + y * 8 + x] : (f16)0;
          }
        }
      for (; k < 168; ++k) rp[k] = (f16)0;
    }
    {
      int4 zz = {0, 0, 0, 0};
      for (int i = tid; i < 18944 / 8; i += 1024) ((int4*)Apmv)[i] = zz;
    }
    __syncthreads();
    // pri: M=64, N=32, 1 tile/wave (waves 0-7), K=160 -> scatter Apmv
    if (wv < 8) {
      int nt = wv & 1, mt = wv >> 1;
      f32x4 a0 = {};
#pragma unroll
      for (int k = 0; k < 160; k += 32) {
        f16x8 bf = *(const f16x8*)(P.wpri + (nt * 16 + lm) * 160 + k + q * 8);
        f16x8 x0 = *(const f16x8*)(Apri + (mt * 16 + lm) * 168 + k + q * 8);
        a0 = MFMA(x0, bf, a0);
      }
      float bb = P.bpri[nt * 16 + lm];
#pragma unroll
      for (int r = 0; r < 4; ++r)
        scat8_lds(Apmv, 296, mt * 16 + q * 4 + r, nt * 16 + lm, fmaxf(a0[r] + bb, 0.f));
    }
    __syncthreads();
    // prim+priv dual: 16 waves = 4 m-tiles x 4 n-quarters, K=288 -> pm, plv
    {
      f32x4 am = {}, av = {};
      int nq = wv & 3, mh = wv >> 2;
      int ch = nq * 16 + lm;
#pragma unroll
      for (int k = 0; k < 288; k += 32) {
        f16x8 bm = *(const f16x8*)(P.wpmv + (long)ch * 288 + k + q * 8);
        f16x8 bv = *(const f16x8*)(P.wpmv + (long)(64 + ch) * 288 + k + q * 8);
        f16x8 a = *(const f16x8*)(Apmv + (mh * 16 + lm) * 296 + k + q * 8);
        am = MFMA(a, bm, am);
        av = MFMA(a, bv, av);
      }
      float bbm = P.bpm[ch], bbv = P.bpv[ch];
#pragma unroll
      for (int r = 0; r < 4; ++r) {
        int pos = mh * 16 + q * 4 + r;
        P.pm[(long)b * 4096 + ch * 64 + pos] = am[r] + bbm;
        P.plv[(long)b * 4096 + ch * 64 + pos] = softplusf_(av[r] + bbv);
      }
    }
    return;
  }

  // ================= tail: dec1 + dec2 for batch b =================
  int b = blockIdx.x;
  f16* Ad1 = slds;               // 20480 (all in-Kc entries written by scatd1 below)
  f16* d1f = slds + 20480;       // [32][240] = 7680
  const f16* gb_ = P.gi + (long)b * 3072;
  // rebuild dec1 class-im2col from gi: h (ic 0..15) + zpsi (ic 16..31), 1 elem each/thread
  {
    int i = tid;
    scatd1_lds(Ad1, i & 63, i >> 6, (float)gb_[2048 + i]);
    scatd1_lds(Ad1, i & 63, 16 + (i >> 6), (float)gb_[1024 + i]);
  }
  __syncthreads();
  // ---- dec1 ConvT via 4 parity-class GEMMs: 2 classes/wave (16 waves) -> d1f ----
  {
    int nt = wv & 1, mt = (wv >> 1) & 3, cb = wv >> 3;  // cb 0..1 -> classes {cb, cb+2}
#pragma unroll
    for (int cc = 0; cc < 2; ++cc) {
      int c = cb + cc * 2;
      int cy = c >> 1, cx = c & 1;
      int Kc = 32 << (cy + cx);
      int Kp = Kc + 8;
      int aof = cy ? (cx ? 11776 : 7168) : (cx ? 2560 : 0);
      int bof = cy ? (cx ? 5120 : 3072) : (cx ? 1024 : 0);
      f32x4 acc = {};
      for (int k = 0; k < Kc; k += 32) {
        f16x8 a = *(const f16x8*)(Ad1 + aof + (mt * 16 + lm) * Kp + k + q * 8);
        f16x8 bf = *(const f16x8*)(P.wd1 + bof + (nt * 16 + lm) * Kc + k + q * 8);
        acc = MFMA(a, bf, acc);
      }
      int oc = nt * 16 + lm;
      float bb = P.bd1[oc];
#pragma unroll
      for (int r = 0; r < 4; ++r) {
        int m = mt * 16 + q * 4 + r;
        int y = 2 * (m >> 3) + cy, x = 2 * (m & 7) + cx;
        if (y < 15 && x < 15)
          d1f[oc * 240 + y * 15 + x] = (f16)fmaxf(acc[r] + bb, 0.f);
      }
    }
  }
  __syncthreads();
  // ---- dec2 ConvT 15->32 (direct, parity x y-quad per wave), sigmoid -> out ----
  {
    int p = wv & 3, jh = wv >> 2;     // jh 0..3
    int cy2 = p >> 1, cx2 = p & 1;
    int lx = lane & 15, ly = lane >> 4;
    int x = 2 * lx + cx2;
    float acc0 = P.d2b[0], acc1 = P.d2b[1], acc2 = P.d2b[2];
    int nky = cy2 ? 1 : 2, nkx = cx2 ? 1 : 2;
    int py = jh * 4 + ly;
    for (int ic = 0; ic < 32; ++ic) {
      const f16* sp = d1f + ic * 240;
      const float* wic = P.d2w + ic * 27;
      for (int ty = 0; ty < nky; ++ty) {
        int ky = cy2 ? 1 : ty * 2;
        int iy = (2 * py + cy2 - ky) >> 1;
        bool yv = (unsigned)iy < 15u;
        for (int tx = 0; tx < nkx; ++tx) {
          int kx = cx2 ? 1 : tx * 2;
          int ix = (x - kx) >> 1;
          if (yv && (unsigned)ix < 15u) {
            float v = (float)sp[iy * 15 + ix];
            acc0 += v * wic[ky * 3 + kx];
            acc1 += v * wic[9 + ky * 3 + kx];
            acc2 += v * wic[18 + ky * 3 + kx];
          }
        }
      }
    }
    int y = 2 * py + cy2;
    P.out_t[(long)b * 82944 + 0 * 1024 + y * 32 + x] = sigmoidf_(acc0);
    P.out_t[(long)b * 82944 + 1 * 1024 + y * 32 + x] = sigmoidf_(acc1);
    P.out_t[(long)b * 82944 + 2 * 1024 + y * 32 + x] = sigmoidf_(acc2);
  }
}

extern "C" void kernel_launch(void* const* d_in, const int* in_sizes, int n_in,
                              void* d_out, int out_size, void* d_ws, size_t ws_size,
                              hipStream_t stream) {
  const float* x       = (const float*)d_in[0];
  const float* eps     = (const float*)d_in[1];
  const float* psix1_w = (const float*)d_in[2];
  const float* psix1_b = (const float*)d_in[3];
  const float* psix2_w = (const float*)d_in[4];
  const float* psix2_b = (const float*)d_in[5];
  const float* psiz_w  = (const float*)d_in[6];
  const float* psiz_b  = (const float*)d_in[7];
  const float* enc1_w  = (const float*)d_in[8];
  const float* enc1_b  = (const float*)d_in[9];
  const float* enc2_w  = (const float*)d_in[10];
  const float* enc2_b  = (const float*)d_in[11];
  const float* encm_w  = (const float*)d_in[12];
  const float* encm_b  = (const float*)d_in[13];
  const float* encv_w  = (const float*)d_in[14];
  const float* encv_b  = (const float*)d_in[15];
  const float* pri_w   = (const float*)d_in[16];
  const float* pri_b   = (const float*)d_in[17];
  const float* prim_w  = (const float*)d_in[18];
  const float* prim_b  = (const float*)d_in[19];
  const float* priv_w  = (const float*)d_in[20];
  const float* priv_b  = (const float*)d_in[21];
  const float* dec1_w  = (const float*)d_in[22];
  const float* dec1_b  = (const float*)d_in[23];
  const float* dec2_w  = (const float*)d_in[24];
  const float* dec2_b  = (const float*)d_in[25];
  const float* gru_wi  = (const float*)d_in[26];
  const float* gru_wh  = (const float*)d_in[27];
  const float* gru_bi  = (const float*)d_in[28];
  const float* gru_bh  = (const float*)d_in[29];

  float* out = (float*)d_out;
  float* zm_out  = out + 10616832;
  float* zlv_out = zm_out + 524288;
  float* pm_out  = zlv_out + 524288;
  float* plv_out = pm_out + 524288;

  f16* ws16 = (f16*)d_ws;
  f16* wi_f  = ws16 + OFF_WI;
  f16* wh_f  = ws16 + OFF_WH;
  f16* w_px1 = ws16 + OFF_WPX1;
  f16* w_px2 = ws16 + OFF_WPX2;
  f16* w_e1  = ws16 + OFF_WE1;
  f16* w_e2  = ws16 + OFF_WE2;
  f16* w_mv  = ws16 + OFF_WMV;
  f16* w_pz  = ws16 + OFF_WPZ;
  f16* w_pri = ws16 + OFF_WPRI;
  f16* w_pmv = ws16 + OFF_WPMV;
  f16* w_d1  = ws16 + OFF_WD1;
  f16* gi    = ws16 + OFF_GI;
  float* fws = (float*)(ws16 + OFF_F16_END);
  float* gih0 = fws;                 // 393216
  float* gih1 = gih0 + 393216;       // 393216
  float* ghh  = gih1 + 393216;       // 393216
  float* hG   = ghh + 393216;        // 131072

  k_wpack<<<2048, 256, 0, stream>>>(gru_wi, wi_f, 3072, 3072, 3072);
  k_wpack<<<1024, 256, 0, stream>>>(gru_wh, wh_f, 3072, 1024, 1024);
  k_wpack<<<2, 256, 0, stream>>>(psix1_w, w_px1, 16, 27, 32);
  k_wpack<<<10, 256, 0, stream>>>(psix2_w, w_px2, 16, 144, 160);
  k_wpack<<<36, 256, 0, stream>>>(enc1_w, w_e1, 32, 288, 288);
  k_wpack<<<72, 256, 0, stream>>>(enc2_w, w_e2, 64, 288, 288);
  k_wpack<<<144, 256, 0, stream>>>(encm_w, w_mv, 64, 576, 576);
  k_wpack<<<144, 256, 0, stream>>>(encv_w, w_mv + 64L * 576, 64, 576, 576);
  k_wpack<<<36, 256, 0, stream>>>(psiz_w, w_pz, 16, 576, 576);
  k_wpack<<<20, 256, 0, stream>>>(pri_w, w_pri, 32, 144, 160);
  k_wpack<<<72, 256, 0, stream>>>(prim_w, w_pmv, 64, 288, 288);
  k_wpack<<<72, 256, 0, stream>>>(priv_w, w_pmv + 64L * 288, 64, 288, 288);
  k_wd1<<<36, 256, 0, stream>>>(dec1_w, w_d1);

  for (int t = 0; t < NSTEP; ++t) {
    Params P;
    P.frame = (t < 6) ? x + (long)t * 3072 : out + (long)(t - 1) * 3072;
    P.fstride = (t < 6) ? 86016 : 82944;
    P.eps_t = eps + (long)t * 524288;
    P.wpx1 = w_px1; P.wpx2 = w_px2; P.we1 = w_e1; P.we2 = w_e2;
    P.wmv = w_mv; P.wpz = w_pz; P.wd1 = w_d1; P.wpri = w_pri; P.wpmv = w_pmv;
    P.wiG = wi_f; P.whG = wh_f;
    P.bpx1 = psix1_b; P.bpx2 = psix2_b; P.be1 = enc1_b; P.be2 = enc2_b;
    P.bm = encm_b; P.bv = encv_b; P.bpz = psiz_b; P.bd1 = dec1_b;
    P.d2w = dec2_w; P.d2b = dec2_b; P.bpri = pri_b; P.bpm = prim_b; P.bpv = priv_b;
    P.gbi = gru_bi; P.gbh = gru_bh;
    P.gih0 = gih0; P.gih1 = gih1; P.ghh = ghh;
    P.hG = hG; P.gi = gi;
    P.out_t = out + (long)t * 3072;
    P.zm = zm_out; P.zlv = zlv_out; P.pm = pm_out; P.plv = plv_out;
    P.t = t; P.last = (t == NSTEP - 1);
    k_head<<<128, 1024, 0, stream>>>(P);
    k_tailgru<<<256, 1024, 0, stream>>>(P);
  }
}

// Round 9
// 2264.846 us; speedup vs baseline: 1.7523x; 1.2003x over previous
//
#include <hip/hip_runtime.h>

#define NSTEP 27

typedef _Float16 f16;
typedef __attribute__((ext_vector_type(8))) _Float16 f16x8;
typedef __attribute__((ext_vector_type(4))) float f32x4;

#define MFMA(a, b, c) __builtin_amdgcn_mfma_f32_16x16x32_f16(a, b, c, 0, 0, 0)

__device__ __forceinline__ float sigmoidf_(float x) { return 1.0f / (1.0f + expf(-x)); }
__device__ __forceinline__ float softplusf_(float x) { return x > 20.0f ? x : log1pf(expf(x)); }

// ---------------- f16 workspace arena ----------------
constexpr long OFF_WI   = 0;                         // [3072][3072]
constexpr long OFF_WH   = OFF_WI   + 3072L * 3072;   // [3072][1024]
constexpr long OFF_WPX1 = OFF_WH   + 3072L * 1024;   // [16][32]
constexpr long OFF_WPX2 = OFF_WPX1 + 512;            // [16][160]
constexpr long OFF_WE1  = OFF_WPX2 + 2560;           // [32][288]
constexpr long OFF_WE2  = OFF_WE1  + 9216;           // [64][288]
constexpr long OFF_WMV  = OFF_WE2  + 18432;          // [128][576]
constexpr long OFF_WPZ  = OFF_WMV  + 73728;          // [16][576]
constexpr long OFF_WPRI = OFF_WPZ  + 9216;           // [32][160]
constexpr long OFF_WPMV = OFF_WPRI + 5120;           // [128][288]
constexpr long OFF_WD1  = OFF_WPMV + 36864;          // [9216] 4 classes
constexpr long OFF_GI   = OFF_WD1  + 9216;           // [128][3072]
constexpr long OFF_F16_END = OFF_GI + 128L * 3072;

struct Params {
  const float* frame; long fstride;
  const float* eps_t;
  const f16 *wpx1, *wpx2, *we1, *we2, *wmv, *wpz, *wd1, *wpri, *wpmv, *wiG, *whG;
  const float *bpx1, *bpx2, *be1, *be2, *bm, *bv, *bpz, *bd1;
  const float *d2w, *d2b, *bpri, *bpm, *bpv, *gbi, *gbh;
  float *gih0, *gih1, *ghh;
  float* hG; f16* gi;
  float *out_t, *zm, *zlv, *pm, *plv;
  int t, last;
};

// scatter fmap value at (pos=py*8+px, ic) into 8x8 s1p1-conv im2col A (padded row stride ldk)
__device__ __forceinline__ void scat8_lds(f16* __restrict__ A, int ldk, int pos, int ic, float val) {
  int py = pos >> 3, px = pos & 7;
  f16 v = (f16)val;
#pragma unroll
  for (int ky = 0; ky < 3; ++ky) {
    int oy = py + 1 - ky;
    if ((unsigned)oy >= 8u) continue;
#pragma unroll
    for (int kx = 0; kx < 3; ++kx) {
      int ox = px + 1 - kx;
      if ((unsigned)ox >= 8u) continue;
      A[(oy * 8 + ox) * ldk + ic * 9 + ky * 3 + kx] = v;
    }
  }
}

// scatter fmap value into dec1 ConvT (8->15, s2 p1) parity-class im2col (padded strides)
__device__ __forceinline__ void scatd1_lds(f16* __restrict__ Ad1, int pos, int ic, float val) {
  const int aof[4] = {0, 2560, 7168, 11776};
  const int Kp[4] = {40, 72, 72, 136};
  int py = pos >> 3, px = pos & 7;
  f16 v = (f16)val;
#pragma unroll
  for (int ky = 0; ky < 3; ++ky) {
    int y = 2 * py + ky - 1;
    if ((unsigned)y >= 15u) continue;
    int cy = y & 1;
    int nky = cy ? 2 : 1;
    int tiy = cy ? (ky >> 1) : 0;
#pragma unroll
    for (int kx = 0; kx < 3; ++kx) {
      int x = 2 * px + kx - 1;
      if ((unsigned)x >= 15u) continue;
      int cx = x & 1;
      int nkx = cx ? 2 : 1;
      int tix = cx ? (kx >> 1) : 0;
      int c = cy * 2 + cx;
      Ad1[aof[c] + ((y >> 1) * 8 + (x >> 1)) * Kp[c] + ic * (nky * nkx) + tiy * nkx + tix] = v;
    }
  }
}

// one 64x32 GRU GEMM tile (round-2/4 proven shape). tau: z = tau/192, gw = tau%192.
__device__ __forceinline__ void gru_tile(const Params& P, int tau, int lane) {
  int lm = lane & 15, q8 = lane >> 4;
  int z = tau / 192, gw = tau - z * 192;
  int mg = gw & 1, ng = gw >> 1;
  const f16* A = (z == 2) ? P.gi + 2048 : P.gi;
  const f16* B = (z == 2) ? P.whG : P.wiG;
  int K = (z == 2) ? 1024 : 1536;
  int k0 = (z == 1) ? 1536 : 0;
  long ldb = (z == 2) ? 1024 : 3072;
  float* outp = (z == 0) ? P.gih0 : (z == 1) ? P.gih1 : P.ghh;
  int m0 = mg * 64, n0 = ng * 32;
  f32x4 acc[4][2] = {};
  const f16* Ap = A + (long)(m0 + lm) * 3072 + k0 + q8 * 8;
  const f16* Bp = B + (long)(n0 + lm) * ldb + k0 + q8 * 8;
#pragma unroll 2
  for (int k = 0; k < K; k += 32) {
    f16x8 b0 = *(const f16x8*)(Bp + k);
    f16x8 b1 = *(const f16x8*)(Bp + 16 * ldb + k);
#pragma unroll
    for (int i = 0; i < 4; ++i) {
      f16x8 a = *(const f16x8*)(Ap + (long)i * 16 * 3072 + k);
      acc[i][0] = MFMA(a, b0, acc[i][0]);
      acc[i][1] = MFMA(a, b1, acc[i][1]);
    }
  }
#pragma unroll
  for (int i = 0; i < 4; ++i)
#pragma unroll
    for (int j = 0; j < 2; ++j)
#pragma unroll
      for (int r = 0; r < 4; ++r)
        outp[(long)(m0 + i * 16 + q8 * 4 + r) * 3072 + n0 + j * 16 + lm] = acc[i][j][r];
}

// ---------------- setup: weight fp32 -> f16 packing ----------------
__global__ __launch_bounds__(256) void k_wpack(const float* __restrict__ src, f16* __restrict__ dst,
                                               int N, int Ks, int Kd) {
  int tot = N * Kd, stride = gridDim.x * 256;
  for (int i = blockIdx.x * 256 + threadIdx.x; i < tot; i += stride) {
    int n = i / Kd, k = i - n * Kd;
    dst[i] = (k < Ks) ? (f16)src[n * Ks + k] : (f16)0.f;
  }
}

__global__ __launch_bounds__(256) void k_wd1(const float* __restrict__ src, f16* __restrict__ dst) {
  int i = blockIdx.x * 256 + threadIdx.x;
  if (i >= 9216) return;
  int c, base;
  if (i < 1024) { c = 0; base = 0; }
  else if (i < 3072) { c = 1; base = 1024; }
  else if (i < 5120) { c = 2; base = 3072; }
  else { c = 3; base = 5120; }
  const int Kc[4] = {32, 64, 64, 128};
  int j = i - base, K = Kc[c];
  int oc = j / K, k = j - oc * K;
  int cy = c >> 1, cx = c & 1;
  int nky = cy ? 2 : 1, nkx = cx ? 2 : 1, ntap = nky * nkx;
  int ic = k / ntap, tap = k - ic * ntap;
  int tiy = tap / nkx, tix = tap - tiy * nkx;
  int ky = (nky == 1) ? 1 : tiy * 2;
  int kx = (nkx == 1) ? 1 : tix * 2;
  dst[i] = (f16)src[((ic * 32 + oc) * 3 + ky) * 3 + kx];
}

// =================== head kernel: gates ... psiz (round-8 verified) ===================
// 1 block = 1 batch, 1024 threads. Produces gi(t) (psix2/psiz/h) for the tail+GRU kernel.
__global__ __launch_bounds__(1024) void k_head(Params P) {
  __shared__ f16 lds[78336];
  f16* hbuf = lds;
  f16* B1 = lds + 1024;
  f16* B2 = lds + 38400;
  f16* B3 = lds + 57344;
  f16* A1 = B3;
  f16* frame = B3 + 10240;
  f16* A2 = B3 + 10240;

  int b = blockIdx.x, tid = threadIdx.x;
  int wv = tid >> 6, lane = tid & 63, lm = lane & 15, q = lane >> 4;
  f32x4 z4 = {};

  // ---- GRU gates of previous step -> h_t (1 element/thread) ----
  {
    int i = tid;
    float hn = 0.f;
    if (P.t) {
      long o = (long)b * 3072 + i;
      float ir  = P.gih0[o] + P.gih1[o] + P.gbi[i];
      float iz  = P.gih0[o + 1024] + P.gih1[o + 1024] + P.gbi[i + 1024];
      float in_ = P.gih0[o + 2048] + P.gih1[o + 2048] + P.gbi[i + 2048];
      float hr  = P.ghh[o] + P.gbh[i];
      float hz  = P.ghh[o + 1024] + P.gbh[i + 1024];
      float hnn = P.ghh[o + 2048] + P.gbh[i + 2048];
      float r = sigmoidf_(ir + hr), u = sigmoidf_(iz + hz);
      float ng = tanhf(in_ + r * hnn);
      hn = (1.f - u) * ng + u * P.hG[b * 1024 + i];
    }
    P.hG[b * 1024 + i] = hn;
    hbuf[i] = (f16)hn;
    P.gi[(long)b * 3072 + 2048 + i] = (f16)hn;
  }
  // ---- stage input frame ----
  const float* fr = P.frame + (long)b * P.fstride;
  for (int i = tid; i < 3072; i += 1024) frame[i] = (f16)fr[i];
  __syncthreads();
  // ---- A1 build (tid<512, 2 threads/row)  ||  zero B1,B2 (tid>=512) ----
  if (tid < 512) {
    int row = tid >> 1, half = tid & 1;
    int oy = row >> 4, ox = row & 15;
    f16* rp = A1 + row * 40;
    if (half == 0) {
#pragma unroll
      for (int ic = 0; ic < 2; ++ic)
#pragma unroll
        for (int ky = 0; ky < 3; ++ky) {
          int y = 2 * oy + ky - 1;
#pragma unroll
          for (int kx = 0; kx < 3; ++kx) {
            int x = 2 * ox + kx - 1;
            rp[ic * 9 + ky * 3 + kx] =
                ((unsigned)y < 32u && (unsigned)x < 32u) ? frame[ic * 1024 + y * 32 + x] : (f16)0;
          }
        }
    } else {
#pragma unroll
      for (int ky = 0; ky < 3; ++ky) {
        int y = 2 * oy + ky - 1;
#pragma unroll
        for (int kx = 0; kx < 3; ++kx) {
          int x = 2 * ox + kx - 1;
          rp[18 + ky * 3 + kx] =
              ((unsigned)y < 32u && (unsigned)x < 32u) ? frame[2048 + y * 32 + x] : (f16)0;
        }
      }
#pragma unroll
      for (int k = 27; k < 40; ++k) rp[k] = (f16)0;
    }
  } else {
    int4 zz = {0, 0, 0, 0};
    int t2 = tid - 512;
    for (int i = t2; i < 18944 / 8; i += 512) ((int4*)B2)[i] = zz;
    for (int i = t2; i < 37376 / 8; i += 512) ((int4*)B1)[i] = zz;
  }
  __syncthreads();
  // ---- zero A2 (overlays dead frame) ----
  {
    int4 zz = {0, 0, 0, 0};
    for (int i = tid; i < 10752 / 8; i += 1024) ((int4*)A2)[i] = zz;
  }
  __syncthreads();
  // ---- h -> enc1 im2col (ic 16..31), 1 element/thread ----
  scat8_lds(B2, 296, tid & 63, 16 + (tid >> 6), (float)hbuf[tid]);
  // ---- psix1: M=256 (1 m-tile/wave over 16 waves), N=16, K=32; relu -> s2 scatter to A2 ----
  {
    f16x8 bf = *(const f16x8*)(P.wpx1 + lm * 32 + q * 8);
    float bb = P.bpx1[lm];
    int mt = wv;
    f16x8 a = *(const f16x8*)(A1 + (mt * 16 + lm) * 40 + q * 8);
    f32x4 acc = MFMA(a, bf, z4);
#pragma unroll
    for (int r = 0; r < 4; ++r) {
      int m = mt * 16 + q * 4 + r;
      float val = fmaxf(acc[r] + bb, 0.f);
      int y = m >> 4, x = m & 15;
      f16 v = (f16)val;
#pragma unroll
      for (int ky = 0; ky < 3; ++ky) {
        int ty = y + 1 - ky;
        if (ty < 0 || (ty & 1)) continue;
        int oy = ty >> 1; if (oy >= 8) continue;
#pragma unroll
        for (int kx = 0; kx < 3; ++kx) {
          int tx = x + 1 - kx;
          if (tx < 0 || (tx & 1)) continue;
          int ox = tx >> 1; if (ox >= 8) continue;
          A2[(oy * 8 + ox) * 168 + lm * 9 + ky * 3 + kx] = v;
        }
      }
    }
  }
  __syncthreads();
  // ---- psix2: M=64 (waves 0..3), N=16, K=160; relu -> gi + enc1 im2col (ic 0..15) ----
  if (wv < 4) {
    f32x4 acc = {};
#pragma unroll
    for (int k = 0; k < 160; k += 32) {
      f16x8 a = *(const f16x8*)(A2 + (wv * 16 + lm) * 168 + k + q * 8);
      f16x8 bf = *(const f16x8*)(P.wpx2 + lm * 160 + k + q * 8);
      acc = MFMA(a, bf, acc);
    }
    float bb = P.bpx2[lm];
#pragma unroll
    for (int r = 0; r < 4; ++r) {
      int pos = wv * 16 + q * 4 + r;
      float val = fmaxf(acc[r] + bb, 0.f);
      P.gi[(long)b * 3072 + lm * 64 + pos] = (f16)val;
      scat8_lds(B2, 296, pos, lm, val);
    }
  }
  __syncthreads();
  // ---- enc1: waves 0-7 GEMM (M=64,N=32) ----
  {
    int nt = wv & 1, mt = (wv >> 1) & 3;
    f32x4 a0 = {};
    if (wv < 8) {
#pragma unroll
      for (int k = 0; k < 288; k += 32) {
        f16x8 bf = *(const f16x8*)(P.we1 + (nt * 16 + lm) * 288 + k + q * 8);
        f16x8 x0 = *(const f16x8*)(B2 + (mt * 16 + lm) * 296 + k + q * 8);
        a0 = MFMA(x0, bf, a0);
      }
    }
    __syncthreads();
    if (wv < 8) {
      float bb = P.be1[nt * 16 + lm];
#pragma unroll
      for (int r = 0; r < 4; ++r)
        scat8_lds(B2, 296, mt * 16 + q * 4 + r, nt * 16 + lm, fmaxf(a0[r] + bb, 0.f));
    }
  }
  __syncthreads();
  // ---- enc2: M=64 (4 m-tiles), N=64 (4 n-tiles): 1 tile/wave; -> Amv (B1) ----
  {
    int nt = wv & 3, mh = wv >> 2;   // mh 0..3
    f32x4 acc = {};
#pragma unroll
    for (int k = 0; k < 288; k += 32) {
      f16x8 bf = *(const f16x8*)(P.we2 + (nt * 16 + lm) * 288 + k + q * 8);
      f16x8 a = *(const f16x8*)(B2 + ((mh)*16 + lm) * 296 + k + q * 8);
      acc = MFMA(a, bf, acc);
    }
    int ch = nt * 16 + lm;
    float bb = P.be2[ch];
#pragma unroll
    for (int r = 0; r < 4; ++r)
      scat8_lds(B1, 584, mh * 16 + q * 4 + r, ch, fmaxf(acc[r] + bb, 0.f));
  }
  __syncthreads();
  // ---- encm+encv dual: 16 waves = 4 m-tiles x 4 n-quarters, K=576; z -> Apz (B1 in place) ----
  {
    f32x4 am = {}, av = {};
    int nq = wv & 3, mh = wv >> 2;   // mh 0..3
    int ch = nq * 16 + lm;
    const float4 ev = *(const float4*)(P.eps_t + (long)b * 4096 + ch * 64 + mh * 16 + q * 4);
    float evr[4] = {ev.x, ev.y, ev.z, ev.w};
#pragma unroll
    for (int k = 0; k < 576; k += 32) {
      f16x8 bm = *(const f16x8*)(P.wmv + (long)ch * 576 + k + q * 8);
      f16x8 bv = *(const f16x8*)(P.wmv + (long)(64 + ch) * 576 + k + q * 8);
      f16x8 a = *(const f16x8*)(B1 + (mh * 16 + lm) * 584 + k + q * 8);
      am = MFMA(a, bm, am);
      av = MFMA(a, bv, av);
    }
    __syncthreads();
    float bbm = P.bm[ch], bbv = P.bv[ch];
#pragma unroll
    for (int r = 0; r < 4; ++r) {
      int pos = mh * 16 + q * 4 + r;
      float zmv = am[r] + bbm;
      float sp = softplusf_(av[r] + bbv);
      float zval = zmv + sp * evr[r];
      if (P.last) {
        P.zm[(long)b * 4096 + ch * 64 + pos] = zmv;
        P.zlv[(long)b * 4096 + ch * 64 + pos] = sp;
      }
      scat8_lds(B1, 584, pos, ch, zval);
    }
  }
  __syncthreads();
  // ---- psiz: M=64 (waves 0..3), N=16, K=576; relu -> gi (tail kernel rebuilds Ad1) ----
  if (wv < 4) {
    f32x4 acc = {};
#pragma unroll
    for (int k = 0; k < 576; k += 32) {
      f16x8 a = *(const f16x8*)(B1 + (wv * 16 + lm) * 584 + k + q * 8);
      f16x8 bf = *(const f16x8*)(P.wpz + (long)lm * 576 + k + q * 8);
      acc = MFMA(a, bf, acc);
    }
    float bb = P.bpz[lm];
#pragma unroll
    for (int r = 0; r < 4; ++r) {
      int pos = wv * 16 + q * 4 + r;
      float val = fmaxf(acc[r] + bb, 0.f);
      P.gi[(long)b * 3072 + 1024 + lm * 64 + pos] = (f16)val;
    }
  }
}

// =================== tail + GRU kernel (512 thr, grid 416; launch-order synced) ===================
// Blocks 0-127: tail (dec1+dec2) for batch b, 8 waves (round-2 verified tiling, inputs from gi).
// Blocks 128-415: 288 GRU blocks x 2 waves = 576 tiles -> round-4's proven 2.25-waves/CU regime
// spread over the whole chip, starting immediately (gi complete at launch). Tail (VALU/LDS) and
// GRU (vmem) co-reside per CU on complementary pipes. t==26: blocks 128-255 run pri chain.
__global__ __launch_bounds__(512) void k_tailgru(Params P) {
  __shared__ f16 slds[29696];
  int tid = threadIdx.x;
  int wv = tid >> 6, lane = tid & 63, lm = lane & 15, q = lane >> 4;

  if (blockIdx.x >= 128) {
    if (!P.last) {
      // ---- GRU tiles: 2 per block, 1 per wave ----
      int gb = blockIdx.x - 128;             // 0..287
      if (wv < 2) gru_tile(P, gb * 2 + wv, lane);
      return;
    }
    if (blockIdx.x >= 256) return;
    // ---- t==26: pri -> prim/priv for batch b (512-thread round-2 math) ----
    int b = blockIdx.x - 128;
    f16* Apri = slds;              // [64][168] = 10752
    f16* Apmv = slds + 10752;      // [64][296] = 18944
    const f16* hsrc = P.gi + (long)b * 3072 + 2048;
    if (tid < 64) {
      int py = tid >> 3, px = tid & 7;
      f16* rp = Apri + tid * 168;
      int k = 0;
      for (int ic = 0; ic < 16; ++ic)
        for (int ky = 0; ky < 3; ++ky) {
          int y = py + ky - 1;
          for (int kx = 0; kx < 3; ++kx, ++k) {
            int x = px + kx - 1;
            rp[k] = ((unsigned)y < 8u && (unsigned)x < 8u) ? hsrc[ic * 64 + y * 8 + x] : (f16)0;
          }
        }
      for (; k < 168; ++k) rp[k] = (f16)0;
    }
    {
      int4 zz = {0, 0, 0, 0};
      for (int i = tid; i < 18944 / 8; i += 512) ((int4*)Apmv)[i] = zz;
    }
    __syncthreads();
    // pri: M=64, N=32, 1 tile/wave (8 waves), K=160 -> scatter Apmv
    {
      int nt = wv & 1, mt = wv >> 1;
      f32x4 a0 = {};
#pragma unroll
      for (int k = 0; k < 160; k += 32) {
        f16x8 bf = *(const f16x8*)(P.wpri + (nt * 16 + lm) * 160 + k + q * 8);
        f16x8 x0 = *(const f16x8*)(Apri + (mt * 16 + lm) * 168 + k + q * 8);
        a0 = MFMA(x0, bf, a0);
      }
      float bb = P.bpri[nt * 16 + lm];
#pragma unroll
      for (int r = 0; r < 4; ++r)
        scat8_lds(Apmv, 296, mt * 16 + q * 4 + r, nt * 16 + lm, fmaxf(a0[r] + bb, 0.f));
    }
    __syncthreads();
    // prim+priv dual: M=64 (m-split over wave halves), K=288 -> pm, plv
    {
      f32x4 am[2] = {}, av[2] = {};
      int nq = wv & 3, mh = wv >> 2;   // mh 0..1
      int ch = nq * 16 + lm;
#pragma unroll
      for (int k = 0; k < 288; k += 32) {
        f16x8 bm = *(const f16x8*)(P.wpmv + (long)ch * 288 + k + q * 8);
        f16x8 bv = *(const f16x8*)(P.wpmv + (long)(64 + ch) * 288 + k + q * 8);
#pragma unroll
        for (int mi = 0; mi < 2; ++mi) {
          f16x8 a = *(const f16x8*)(Apmv + ((mh * 2 + mi) * 16 + lm) * 296 + k + q * 8);
          am[mi] = MFMA(a, bm, am[mi]);
          av[mi] = MFMA(a, bv, av[mi]);
        }
      }
      float bbm = P.bpm[ch], bbv = P.bpv[ch];
#pragma unroll
      for (int mi = 0; mi < 2; ++mi)
#pragma unroll
        for (int r = 0; r < 4; ++r) {
          int pos = (mh * 2 + mi) * 16 + q * 4 + r;
          P.pm[(long)b * 4096 + ch * 64 + pos] = am[mi][r] + bbm;
          P.plv[(long)b * 4096 + ch * 64 + pos] = softplusf_(av[mi][r] + bbv);
        }
    }
    return;
  }

  // ================= tail: dec1 + dec2 for batch b (8 waves, round-2 tiling) =================
  int b = blockIdx.x;
  f16* Ad1 = slds;               // 20480
  f16* d1f = slds + 20480;       // [32][240] = 7680
  const f16* gb_ = P.gi + (long)b * 3072;
  // rebuild dec1 class-im2col from gi: h (ic 0..15) + zpsi (ic 16..31), 2 elems each/thread
  {
    int i = tid;
    scatd1_lds(Ad1, i & 63, i >> 6, (float)gb_[2048 + i]);
    scatd1_lds(Ad1, i & 63, 16 + (i >> 6), (float)gb_[1024 + i]);
    int i2 = tid + 512;
    scatd1_lds(Ad1, i2 & 63, i2 >> 6, (float)gb_[2048 + i2]);
    scatd1_lds(Ad1, i2 & 63, 16 + (i2 >> 6), (float)gb_[1024 + i2]);
  }
  __syncthreads();
  // ---- dec1 ConvT via 4 parity-class GEMMs: 1 (mt,nt) pair/wave, 4 classes serial ----
  {
    const int Kc[4] = {32, 64, 64, 128};
    const int Kp[4] = {40, 72, 72, 136};
    const int aof[4] = {0, 2560, 7168, 11776};
    const int bof[4] = {0, 1024, 3072, 5120};
    int nt = wv & 1, mt = wv >> 1;
#pragma unroll
    for (int c = 0; c < 4; ++c) {
      int cy = c >> 1, cx = c & 1;
      f32x4 acc = {};
      for (int k = 0; k < Kc[c]; k += 32) {
        f16x8 a = *(const f16x8*)(Ad1 + aof[c] + (mt * 16 + lm) * Kp[c] + k + q * 8);
        f16x8 bf = *(const f16x8*)(P.wd1 + bof[c] + (nt * 16 + lm) * Kc[c] + k + q * 8);
        acc = MFMA(a, bf, acc);
      }
      int oc = nt * 16 + lm;
      float bb = P.bd1[oc];
#pragma unroll
      for (int r = 0; r < 4; ++r) {
        int m = mt * 16 + q * 4 + r;
        int y = 2 * (m >> 3) + cy, x = 2 * (m & 7) + cx;
        if (y < 15 && x < 15)
          d1f[oc * 240 + y * 15 + x] = (f16)fmaxf(acc[r] + bb, 0.f);
      }
    }
  }
  __syncthreads();
  // ---- dec2 ConvT 15->32 (direct, parity x j-half per wave), sigmoid -> out ----
  {
    int p = wv & 3, jh = wv >> 2;
    int cy2 = p >> 1, cx2 = p & 1;
    int lx = lane & 15, ly = lane >> 4;
    int x = 2 * lx + cx2;
    float b0 = P.d2b[0], b1 = P.d2b[1], b2 = P.d2b[2];
    float acc[2][3];
#pragma unroll
    for (int j = 0; j < 2; ++j) { acc[j][0] = b0; acc[j][1] = b1; acc[j][2] = b2; }
    int nky = cy2 ? 1 : 2, nkx = cx2 ? 1 : 2;
    for (int ic = 0; ic < 32; ++ic) {
      const f16* sp = d1f + ic * 240;
      const float* wic = P.d2w + ic * 27;
      for (int ty = 0; ty < nky; ++ty) {
        int ky = cy2 ? 1 : ty * 2;
        for (int tx = 0; tx < nkx; ++tx) {
          int kx = cx2 ? 1 : tx * 2;
          int ix = (x - kx) >> 1;
          bool xv = (unsigned)ix < 15u;
          float w0 = wic[ky * 3 + kx];
          float w1 = wic[9 + ky * 3 + kx];
          float w2 = wic[18 + ky * 3 + kx];
#pragma unroll
          for (int j = 0; j < 2; ++j) {
            int py = (jh * 2 + j) * 4 + ly;
            int iy = (2 * py + cy2 - ky) >> 1;
            if (xv && (unsigned)iy < 15u) {
              float v = (float)sp[iy * 15 + ix];
              acc[j][0] += v * w0; acc[j][1] += v * w1; acc[j][2] += v * w2;
            }
          }
        }
      }
    }
#pragma unroll
    for (int j = 0; j < 2; ++j) {
      int y = 2 * ((jh * 2 + j) * 4 + ly) + cy2;
#pragma unroll
      for (int oc = 0; oc < 3; ++oc)
        P.out_t[(long)b * 82944 + oc * 1024 + y * 32 + x] = sigmoidf_(acc[j][oc]);
    }
  }
}

extern "C" void kernel_launch(void* const* d_in, const int* in_sizes, int n_in,
                              void* d_out, int out_size, void* d_ws, size_t ws_size,
                              hipStream_t stream) {
  const float* x       = (const float*)d_in[0];
  const float* eps     = (const float*)d_in[1];
  const float* psix1_w = (const float*)d_in[2];
  const float* psix1_b = (const float*)d_in[3];
  const float* psix2_w = (const float*)d_in[4];
  const float* psix2_b = (const float*)d_in[5];
  const float* psiz_w  = (const float*)d_in[6];
  const float* psiz_b  = (const float*)d_in[7];
  const float* enc1_w  = (const float*)d_in[8];
  const float* enc1_b  = (const float*)d_in[9];
  const float* enc2_w  = (const float*)d_in[10];
  const float* enc2_b  = (const float*)d_in[11];
  const float* encm_w  = (const float*)d_in[12];
  const float* encm_b  = (const float*)d_in[13];
  const float* encv_w  = (const float*)d_in[14];
  const float* encv_b  = (const float*)d_in[15];
  const float* pri_w   = (const float*)d_in[16];
  const float* pri_b   = (const float*)d_in[17];
  const float* prim_w  = (const float*)d_in[18];
  const float* prim_b  = (const float*)d_in[19];
  const float* priv_w  = (const float*)d_in[20];
  const float* priv_b  = (const float*)d_in[21];
  const float* dec1_w  = (const float*)d_in[22];
  const float* dec1_b  = (const float*)d_in[23];
  const float* dec2_w  = (const float*)d_in[24];
  const float* dec2_b  = (const float*)d_in[25];
  const float* gru_wi  = (const float*)d_in[26];
  const float* gru_wh  = (const float*)d_in[27];
  const float* gru_bi  = (const float*)d_in[28];
  const float* gru_bh  = (const float*)d_in[29];

  float* out = (float*)d_out;
  float* zm_out  = out + 10616832;
  float* zlv_out = zm_out + 524288;
  float* pm_out  = zlv_out + 524288;
  float* plv_out = pm_out + 524288;

  f16* ws16 = (f16*)d_ws;
  f16* wi_f  = ws16 + OFF_WI;
  f16* wh_f  = ws16 + OFF_WH;
  f16* w_px1 = ws16 + OFF_WPX1;
  f16* w_px2 = ws16 + OFF_WPX2;
  f16* w_e1  = ws16 + OFF_WE1;
  f16* w_e2  = ws16 + OFF_WE2;
  f16* w_mv  = ws16 + OFF_WMV;
  f16* w_pz  = ws16 + OFF_WPZ;
  f16* w_pri = ws16 + OFF_WPRI;
  f16* w_pmv = ws16 + OFF_WPMV;
  f16* w_d1  = ws16 + OFF_WD1;
  f16* gi    = ws16 + OFF_GI;
  float* fws = (float*)(ws16 + OFF_F16_END);
  float* gih0 = fws;                 // 393216
  float* gih1 = gih0 + 393216;       // 393216
  float* ghh  = gih1 + 393216;       // 393216
  float* hG   = ghh + 393216;        // 131072

  k_wpack<<<2048, 256, 0, stream>>>(gru_wi, wi_f, 3072, 3072, 3072);
  k_wpack<<<1024, 256, 0, stream>>>(gru_wh, wh_f, 3072, 1024, 1024);
  k_wpack<<<2, 256, 0, stream>>>(psix1_w, w_px1, 16, 27, 32);
  k_wpack<<<10, 256, 0, stream>>>(psix2_w, w_px2, 16, 144, 160);
  k_wpack<<<36, 256, 0, stream>>>(enc1_w, w_e1, 32, 288, 288);
  k_wpack<<<72, 256, 0, stream>>>(enc2_w, w_e2, 64, 288, 288);
  k_wpack<<<144, 256, 0, stream>>>(encm_w, w_mv, 64, 576, 576);
  k_wpack<<<144, 256, 0, stream>>>(encv_w, w_mv + 64L * 576, 64, 576, 576);
  k_wpack<<<36, 256, 0, stream>>>(psiz_w, w_pz, 16, 576, 576);
  k_wpack<<<20, 256, 0, stream>>>(pri_w, w_pri, 32, 144, 160);
  k_wpack<<<72, 256, 0, stream>>>(prim_w, w_pmv, 64, 288, 288);
  k_wpack<<<72, 256, 0, stream>>>(priv_w, w_pmv + 64L * 288, 64, 288, 288);
  k_wd1<<<36, 256, 0, stream>>>(dec1_w, w_d1);

  for (int t = 0; t < NSTEP; ++t) {
    Params P;
    P.frame = (t < 6) ? x + (long)t * 3072 : out + (long)(t - 1) * 3072;
    P.fstride = (t < 6) ? 86016 : 82944;
    P.eps_t = eps + (long)t * 524288;
    P.wpx1 = w_px1; P.wpx2 = w_px2; P.we1 = w_e1; P.we2 = w_e2;
    P.wmv = w_mv; P.wpz = w_pz; P.wd1 = w_d1; P.wpri = w_pri; P.wpmv = w_pmv;
    P.wiG = wi_f; P.whG = wh_f;
    P.bpx1 = psix1_b; P.bpx2 = psix2_b; P.be1 = enc1_b; P.be2 = enc2_b;
    P.bm = encm_b; P.bv = encv_b; P.bpz = psiz_b; P.bd1 = dec1_b;
    P.d2w = dec2_w; P.d2b = dec2_b; P.bpri = pri_b; P.bpm = prim_b; P.bpv = priv_b;
    P.gbi = gru_bi; P.gbh = gru_bh;
    P.gih0 = gih0; P.gih1 = gih1; P.ghh = ghh;
    P.hG = hG; P.gi = gi;
    P.out_t = out + (long)t * 3072;
    P.zm = zm_out; P.zlv = zlv_out; P.pm = pm_out; P.plv = plv_out;
    P.t = t; P.last = (t == NSTEP - 1);
    k_head<<<128, 1024, 0, stream>>>(P);
    k_tailgru<<<416, 512, 0, stream>>>(P);
  }
}